// Round 3
// baseline (1333.069 us; speedup 1.0000x reference)
//
#include <hip/hip_runtime.h>
#include <math.h>

#define NT 4096
#define NA 4096
#define NS 1024
#define NALL 9216
#define NBLK 32   // NT/128

typedef __bf16 bf16_t;
typedef bf16_t bf16x8 __attribute__((ext_vector_type(8)));
typedef float f32x4 __attribute__((ext_vector_type(4)));

static __device__ __forceinline__ f32x4 mfma_bf16(bf16x8 a, bf16x8 b, f32x4 c) {
  return __builtin_amdgcn_mfma_f32_16x16x32_bf16(a, b, c, 0, 0, 0);
}

// ---------------- small prep kernels ----------------

__global__ void k_weights(const float* __restrict__ sg, const float* __restrict__ ff,
                          const float* __restrict__ f4, float* __restrict__ w8) {
  float m = fmaxf(sg[0], sg[1]);
  float e0 = expf(sg[0] - m), e1 = expf(sg[1] - m);
  w8[0] = e0 / (e0 + e1); w8[1] = e1 / (e0 + e1);
  m = fmaxf(ff[0], ff[1]);
  e0 = expf(ff[0] - m); e1 = expf(ff[1] - m);
  w8[2] = e0 / (e0 + e1); w8[3] = e1 / (e0 + e1);
  m = fmaxf(fmaxf(f4[0], f4[1]), fmaxf(f4[2], f4[3]));
  float a0 = expf(f4[0] - m), a1 = expf(f4[1] - m), a2 = expf(f4[2] - m), a3 = expf(f4[3] - m);
  float s = a0 + a1 + a2 + a3;
  w8[4] = a0 / s; w8[5] = a1 / s; w8[6] = a2 / s; w8[7] = a3 / s;
}

// V[r, h*D+d] = (src[r,d]*w[h,d]) / max(||src[r,:]*w[h,:]||, 1e-12), output bf16
__global__ void k_rownorm(const float* __restrict__ src, int D,
                          const float* __restrict__ w, bf16_t* __restrict__ V) {
  int r = blockIdx.x;
  int t = threadIdx.x;  // 64 threads = 1 wave
  const float* x = src + (size_t)r * D;
  bf16_t* out = V + (size_t)r * (2 * D);
  for (int h = 0; h < 2; ++h) {
    float ss = 0.f;
    for (int d = t; d < D; d += 64) {
      float y = x[d] * w[h * D + d];
      ss = fmaf(y, y, ss);
    }
    for (int off = 32; off; off >>= 1) ss += __shfl_xor(ss, off);
    float nrm = fmaxf(sqrtf(ss), 1e-12f);
    for (int d = t; d < D; d += 64) {
      float y = x[d] * w[h * D + d];
      out[h * D + d] = (bf16_t)(y / nrm);
    }
  }
}

// out[r,0:128] = sum_c adj[r, colbase+c] * feats[c, 0:128]   (adj ~0.5% dense; ballot scan)
__global__ void k_spmm128(const float* __restrict__ adj, int colbase, int ncols,
                          const float* __restrict__ feats, float* __restrict__ out) {
  int r = blockIdx.x, t = threadIdx.x, wv = t >> 6, lane = t & 63;  // 128 thr = 2 waves
  const float* arow = adj + (size_t)r * NALL + colbase;
  float acc0 = 0.f, acc1 = 0.f;
  for (int c0 = wv * 64; c0 < ncols; c0 += 128) {
    float a = arow[c0 + lane];
    unsigned long long m = __ballot(a != 0.f);
    while (m) {
      int b = __builtin_ctzll(m); m &= m - 1;
      float v = __shfl(a, b);
      const float* f = feats + (size_t)(c0 + b) * 128;
      acc0 = fmaf(v, f[lane], acc0);
      acc1 = fmaf(v, f[lane + 64], acc1);
    }
  }
  __shared__ float red[2][128];
  red[wv][lane] = acc0; red[wv][lane + 64] = acc1;
  __syncthreads();
  if (t < 128) out[(size_t)r * 128 + t] = red[0][t] + red[1][t];
}

// out[r,0:64] = sum_c adj[r, colbase+c] * S[c,0:64] + bias
__global__ void k_spmm64(const float* __restrict__ adj, int colbase, int ncols,
                         const float* __restrict__ S, const float* __restrict__ bias,
                         float* __restrict__ out) {
  int r = blockIdx.x, t = threadIdx.x, wv = t >> 6, lane = t & 63;  // 128 thr = 2 waves
  const float* arow = adj + (size_t)r * NALL + colbase;
  float acc = 0.f;
  for (int c0 = wv * 64; c0 < ncols; c0 += 128) {
    float a = arow[c0 + lane];
    unsigned long long m = __ballot(a != 0.f);
    while (m) {
      int b = __builtin_ctzll(m); m &= m - 1;
      float v = __shfl(a, b);
      acc = fmaf(v, S[(size_t)(c0 + b) * 64 + lane], acc);
    }
  }
  __shared__ float red[2][64];
  red[wv][lane] = acc;
  __syncthreads();
  if (t < 64) out[(size_t)r * 64 + t] = red[0][t] + red[1][t] + bias[t];
}

// Wt[n][k] = (bf16) W[k][n]   (W: [K][64] f32)
__global__ void k_transp(const float* __restrict__ W, int K, bf16_t* __restrict__ Wt) {
  int idx = blockIdx.x * 256 + threadIdx.x;
  int n = idx & 63, k = idx >> 6;
  if (k < K) Wt[(size_t)n * K + k] = (bf16_t)W[(size_t)k * 64 + n];
}

// ---------------- MFMA Gram tile core (templated fragment shape) ----------------
// Wave computes (MF*16) x (NF*16) tile of V * V^T. Both operands loaded as ROWS of V
// with identical lane patterns (k-permutation invariance makes A/B layout robust).

template <int MF, int NF>
static __device__ __forceinline__ void gram_tile(const bf16_t* __restrict__ V, int ldv, int K,
                                                 int r0w, int c0w, int rq, int kq,
                                                 f32x4 acc[MF][NF]) {
  const bf16_t* Ap = V + (size_t)(r0w + rq) * ldv + kq * 8;
  const bf16_t* Bp = V + (size_t)(c0w + rq) * ldv + kq * 8;
#pragma unroll 2
  for (int kc = 0; kc < K; kc += 32) {
    bf16x8 a[MF], b[NF];
#pragma unroll
    for (int f = 0; f < MF; ++f) a[f] = *(const bf16x8*)(Ap + (size_t)(f * 16) * ldv + kc);
#pragma unroll
    for (int f = 0; f < NF; ++f) b[f] = *(const bf16x8*)(Bp + (size_t)(f * 16) * ldv + kc);
#pragma unroll
    for (int fi = 0; fi < MF; ++fi)
#pragma unroll
      for (int fj = 0; fj < NF; ++fj)
        acc[fi][fj] = mfma_bf16(a[fi], b[fj], acc[fi][fj]);
  }
}

// sim[r,c] = thresh(0.5 * V[r].V[c]) -> bf16 output, row length R
__global__ __launch_bounds__(256, 2) void k_gram_sim(const bf16_t* __restrict__ V, int R, int K,
                                                     float th, bf16_t* __restrict__ out) {
  int tid = threadIdx.x, lane = tid & 63, w = tid >> 6;
  int wr = w >> 1, wc = w & 1, rq = lane & 15, kq = lane >> 4;
  int r0w = blockIdx.y * 128 + wr * 64, c0w = blockIdx.x * 128 + wc * 64;
  f32x4 acc[4][4];
#pragma unroll
  for (int i = 0; i < 4; ++i)
#pragma unroll
    for (int j = 0; j < 4; ++j) acc[i][j] = 0.f;
  gram_tile<4, 4>(V, K, K, r0w, c0w, rq, kq, acc);
#pragma unroll
  for (int fi = 0; fi < 4; ++fi)
#pragma unroll
    for (int fj = 0; fj < 4; ++fj)
#pragma unroll
      for (int reg = 0; reg < 4; ++reg) {
        float s = 0.5f * acc[fi][fj][reg];
        int row = r0w + fi * 16 + kq * 4 + reg;
        int col = c0w + fj * 16 + rq;
        out[(size_t)row * R + col] = (bf16_t)((s < th) ? 0.f : s);
      }
}

// all-7-channel thresholded column sums -> cs[7][NT] (atomic)
// 512 threads = 8 waves of 64x32; block tile 128x128; full grid (spill-proof regs)
__global__ __launch_bounds__(512, 4) void k_colsum_all(
    const bf16_t* __restrict__ Vg, const bf16_t* __restrict__ Vpap, const bf16_t* __restrict__ Vpsp,
    const bf16_t* __restrict__ Vf0, const bf16_t* __restrict__ Vf1,
    const bf16_t* __restrict__ Vs0, const bf16_t* __restrict__ Vs1,
    float* __restrict__ cs) {
  int tid = threadIdx.x, lane = tid & 63, w = tid >> 6;
  int wr = w >> 2, wc = w & 3, rq = lane & 15, kq = lane >> 4;
  int flat = blockIdx.x;
  int swz = (flat & 7) * (NBLK * NBLK / 8) + (flat >> 3);  // XCD swizzle (1024 % 8 == 0)
  int bi = swz >> 5, bj = swz & 31;
  int r0w = bi * 128 + wr * 64, c0w = bj * 128 + wc * 32;
  const bf16_t* const Vp[7] = {Vg, Vpap, Vpsp, Vf0, Vf1, Vs0, Vs1};
  const int Ks[7] = {256, 128, 128, 256, 256, 128, 128};
  const float ths[7] = {0.1f, 0.1f, 0.1f, 0.2f, 0.2f, 0.1f, 0.1f};
#pragma unroll
  for (int ch = 0; ch < 7; ++ch) {
    f32x4 acc[4][2];
#pragma unroll
    for (int i = 0; i < 4; ++i)
#pragma unroll
      for (int j = 0; j < 2; ++j) acc[i][j] = 0.f;
    gram_tile<4, 2>(Vp[ch], Ks[ch], Ks[ch], r0w, c0w, rq, kq, acc);
    float th = ths[ch];
    float part[2] = {0.f, 0.f};
#pragma unroll
    for (int fi = 0; fi < 4; ++fi)
#pragma unroll
      for (int fj = 0; fj < 2; ++fj)
#pragma unroll
        for (int reg = 0; reg < 4; ++reg) {
          float s = 0.5f * acc[fi][fj][reg];
          if (s >= th) part[fj] += s;
        }
#pragma unroll
    for (int fj = 0; fj < 2; ++fj) {
      float p = part[fj];
      p += __shfl_xor(p, 16);
      p += __shfl_xor(p, 32);
      if (kq == 0) atomicAdd(&cs[ch * NT + c0w + fj * 16 + rq], p);
    }
  }
}

// per-column combine coefficients from colsums + softmaxed agg weights
__global__ void k_coef(const float* __restrict__ cs, const float* __restrict__ w8,
                       float* __restrict__ coef) {
  int c = blockIdx.x * 256 + threadIdx.x;
  if (c >= NT) return;
  float csg = cs[c], cspap = cs[NT + c], cspsp = cs[2 * NT + c];
  float csf0 = cs[3 * NT + c], csf1 = cs[4 * NT + c];
  float css0 = cs[5 * NT + c], css1 = cs[6 * NT + c];
  float wS0 = w8[0], wS1 = w8[1], wFF0 = w8[2], wFF1 = w8[3];
  float wF0 = w8[4], wF1 = w8[5], wF2 = w8[6], wF3 = w8[7];
  auto mx = [](float x) { return fmaxf(x, 1e-12f); };
  auto ind = [](float x) { return x > 0.f ? 1.f : 0.f; };
  float cssem = wS0 * ind(cspap) + wS1 * ind(cspsp);
  float csfp = wFF0 * ind(csf0) + wFF1 * ind(csf1);
  float cstt = wFF0 * ind(css0) + wFF1 * ind(css1);
  coef[c]          = wF0 / mx(csg);
  coef[NT + c]     = wF1 * wS0 / (mx(cspap) * mx(cssem));
  coef[2 * NT + c] = wF1 * wS1 / (mx(cspsp) * mx(cssem));
  coef[3 * NT + c] = wF2 * wFF0 / (mx(csf0) * mx(csfp));
  coef[4 * NT + c] = wF2 * wFF1 / (mx(csf1) * mx(csfp));
  coef[5 * NT + c] = wF3 * wFF0 / (mx(css0) * mx(cstt));
  coef[6 * NT + c] = wF3 * wFF1 / (mx(css1) * mx(cstt));
}

// sym[r,c] = sum_ch (coef[r]+coef[c]) * M_ch[r,c]; triangle blocks only; mirror written
// via per-wave LDS transpose; finalcs gets col sums (normal) + row sums (mirror cols).
__global__ __launch_bounds__(512, 4) void k_combine(
    const bf16_t* __restrict__ Vg, const bf16_t* __restrict__ Vpap, const bf16_t* __restrict__ Vpsp,
    const bf16_t* __restrict__ Vf0, const bf16_t* __restrict__ Vf1,
    const bf16_t* __restrict__ Vs0, const bf16_t* __restrict__ Vs1,
    const float* __restrict__ coef, float* __restrict__ outAdj, float* __restrict__ finalcs) {
  __shared__ float ldsT[8][32 * 64];  // 64 KiB: per-wave 32x64 transpose scratch
  int tid = threadIdx.x, lane = tid & 63, w = tid >> 6;
  int wr = w >> 2, wc = w & 3, rq = lane & 15, kq = lane >> 4;
  // triangle decode with XCD swizzle (528 blocks, 528 % 8 == 0)
  int flat = blockIdx.x;
  int swz = (flat & 7) * 66 + (flat >> 3);
  int bi = 0, rem = swz;
  while (rem >= NBLK - bi) { rem -= NBLK - bi; ++bi; }
  int bj = bi + rem;
  int r0w = bi * 128 + wr * 64, c0w = bj * 128 + wc * 32;
  const bf16_t* const Vp[7] = {Vg, Vpap, Vpsp, Vf0, Vf1, Vs0, Vs1};
  const int Ks[7] = {256, 128, 128, 256, 256, 128, 128};
  const float ths[7] = {0.1f, 0.1f, 0.1f, 0.2f, 0.2f, 0.1f, 0.1f};
  f32x4 comb[4][2];
#pragma unroll
  for (int i = 0; i < 4; ++i)
#pragma unroll
    for (int j = 0; j < 2; ++j) comb[i][j] = 0.f;
#pragma unroll
  for (int ch = 0; ch < 7; ++ch) {
    f32x4 acc[4][2];
#pragma unroll
    for (int i = 0; i < 4; ++i)
#pragma unroll
      for (int j = 0; j < 2; ++j) acc[i][j] = 0.f;
    gram_tile<4, 2>(Vp[ch], Ks[ch], Ks[ch], r0w, c0w, rq, kq, acc);
    float th = ths[ch];
    const float* cf = coef + ch * NT;
    float cc0 = cf[c0w + rq], cc1 = cf[c0w + 16 + rq];
#pragma unroll
    for (int fi = 0; fi < 4; ++fi) {
      f32x4 cr = *(const f32x4*)&cf[r0w + fi * 16 + kq * 4];
#pragma unroll
      for (int fj = 0; fj < 2; ++fj) {
        float cc_ = fj ? cc1 : cc0;
#pragma unroll
        for (int reg = 0; reg < 4; ++reg) {
          float s = 0.5f * acc[fi][fj][reg];
          if (s >= th) comb[fi][fj][reg] = fmaf(cr[reg] + cc_, s, comb[fi][fj][reg]);
        }
      }
    }
  }
  // normal-direction write + column partial sums
  float part[2] = {0.f, 0.f};
#pragma unroll
  for (int fi = 0; fi < 4; ++fi)
#pragma unroll
    for (int fj = 0; fj < 2; ++fj)
#pragma unroll
      for (int reg = 0; reg < 4; ++reg) {
        float v = comb[fi][fj][reg];
        int row = r0w + fi * 16 + kq * 4 + reg;
        int col = c0w + fj * 16 + rq;
        outAdj[(size_t)row * NT + col] = v;
        part[fj] += v;
      }
#pragma unroll
  for (int fj = 0; fj < 2; ++fj) {
    float p = part[fj];
    p += __shfl_xor(p, 16);
    p += __shfl_xor(p, 32);
    if (kq == 0) atomicAdd(&finalcs[c0w + fj * 16 + rq], p);
  }
  if (bi != bj) {
    // mirror write via per-wave LDS transpose (XOR-swizzled to spread banks)
    float* T = ldsT[w];
#pragma unroll
    for (int fi = 0; fi < 4; ++fi)
#pragma unroll
      for (int fj = 0; fj < 2; ++fj)
#pragma unroll
        for (int reg = 0; reg < 4; ++reg) {
          int r = fi * 16 + kq * 4 + reg;  // local row   [0,64)
          int c = fj * 16 + rq;            // local col   [0,32)
          T[c * 64 + (r ^ ((c & 15) << 2))] = comb[fi][fj][reg];
        }
    // wave-private LDS: no barrier needed (compiler orders ds ops within wave)
    float rsum = 0.f;
    for (int c = 0; c < 32; ++c) {
      float v = T[c * 64 + (lane ^ ((c & 15) << 2))];
      rsum += v;
      outAdj[(size_t)(c0w + c) * NT + r0w + lane] = v;
    }
    atomicAdd(&finalcs[r0w + lane], rsum);  // mirror-block column sums = row sums
  }
}

__global__ void k_scale(float* __restrict__ adj, const float* __restrict__ finalcs) {
  size_t idx = (size_t)blockIdx.x * 256 + threadIdx.x;
  int c = (int)(idx & (NT - 1));
  adj[idx] = adj[idx] / fmaxf(finalcs[c], 1e-12f);
}

// C[M][64] (f32, atomic) += Arows(bf16 [M][K]) . Brows(bf16 [64][K]) over K-chunk
__global__ __launch_bounds__(256, 2) void k_gemmT(const bf16_t* __restrict__ A,
                                                  const bf16_t* __restrict__ Bt,
                                                  float* __restrict__ C, int K, int kchunk) {
  int tid = threadIdx.x, lane = tid & 63, w = tid >> 6;
  int rq = lane & 15, kq = lane >> 4;
  int r0 = blockIdx.x * 128 + w * 32;
  int kb = blockIdx.y * kchunk;
  f32x4 acc[2][4];
#pragma unroll
  for (int i = 0; i < 2; ++i)
#pragma unroll
    for (int j = 0; j < 4; ++j) acc[i][j] = 0.f;
  const bf16_t* Ap = A + (size_t)(r0 + rq) * K + kb + kq * 8;
  const bf16_t* Bp = Bt + (size_t)rq * K + kb + kq * 8;
#pragma unroll 2
  for (int kc = 0; kc < kchunk; kc += 32) {
    bf16x8 a[2], b[4];
#pragma unroll
    for (int f = 0; f < 2; ++f) a[f] = *(const bf16x8*)(Ap + (size_t)(f * 16) * K + kc);
#pragma unroll
    for (int f = 0; f < 4; ++f) b[f] = *(const bf16x8*)(Bp + (size_t)(f * 16) * K + kc);
#pragma unroll
    for (int fi = 0; fi < 2; ++fi)
#pragma unroll
      for (int fj = 0; fj < 4; ++fj)
        acc[fi][fj] = mfma_bf16(a[fi], b[fj], acc[fi][fj]);
  }
#pragma unroll
  for (int fi = 0; fi < 2; ++fi)
#pragma unroll
    for (int fj = 0; fj < 4; ++fj)
#pragma unroll
      for (int reg = 0; reg < 4; ++reg) {
        int row = r0 + fi * 16 + kq * 4 + reg;
        int col = fj * 16 + rq;
        atomicAdd(&C[(size_t)row * 64 + col], acc[fi][fj][reg]);
      }
}

// ---------------- f32 tile GEMMs (precision-sensitive tail) ----------------

__global__ __launch_bounds__(256) void k_gemm_n64(const float* __restrict__ A, int K,
                                                  const float* __restrict__ B,
                                                  float* __restrict__ C,
                                                  const float* __restrict__ bias, int relu) {
  __shared__ float As[64][68], Bs[64][68];
  int r0 = blockIdx.x * 64;
  int tid = threadIdx.x, tx = tid & 15, ty = tid >> 4;
  float acc[4][4] = {};
  for (int kc = 0; kc < K; kc += 64) {
    __syncthreads();
#pragma unroll
    for (int m = 0; m < 16; ++m) {
      int lin = tid + 256 * m;
      int row = lin >> 6, col = lin & 63;
      As[col][row] = A[(size_t)(r0 + row) * K + kc + col];
      Bs[row][col] = B[(size_t)(kc + row) * 64 + col];
    }
    __syncthreads();
#pragma unroll 8
    for (int k = 0; k < 64; ++k) {
      float a[4], b[4];
#pragma unroll
      for (int i = 0; i < 4; ++i) a[i] = As[k][ty * 4 + i];
#pragma unroll
      for (int j = 0; j < 4; ++j) b[j] = Bs[k][tx * 4 + j];
#pragma unroll
      for (int i = 0; i < 4; ++i)
#pragma unroll
        for (int j = 0; j < 4; ++j)
          acc[i][j] = fmaf(a[i], b[j], acc[i][j]);
    }
  }
#pragma unroll
  for (int i = 0; i < 4; ++i)
#pragma unroll
    for (int j = 0; j < 4; ++j) {
      float v = acc[i][j];
      if (bias) v += bias[tx * 4 + j];
      if (relu) v = fmaxf(v, 0.f);
      C[(size_t)(r0 + ty * 4 + i) * 64 + tx * 4 + j] = v;
    }
}

// split-K f32: C[M][64] += A[M][K-chunk] @ B[K][64]  (atomic)
__global__ __launch_bounds__(256) void k_gemm_n64_sk(const float* __restrict__ A, int K,
                                                     int kchunk, const float* __restrict__ B,
                                                     float* __restrict__ C) {
  __shared__ float As[64][68], Bs[64][68];
  int r0 = blockIdx.x * 64;
  int kb = blockIdx.y * kchunk;
  int tid = threadIdx.x, tx = tid & 15, ty = tid >> 4;
  float acc[4][4] = {};
  for (int kc = kb; kc < kb + kchunk; kc += 64) {
    __syncthreads();
#pragma unroll
    for (int m = 0; m < 16; ++m) {
      int lin = tid + 256 * m;
      int row = lin >> 6, col = lin & 63;
      As[col][row] = A[(size_t)(r0 + row) * K + kc + col];
      Bs[row][col] = B[(size_t)(kc + row) * 64 + col];
    }
    __syncthreads();
#pragma unroll 8
    for (int k = 0; k < 64; ++k) {
      float a[4], b[4];
#pragma unroll
      for (int i = 0; i < 4; ++i) a[i] = As[k][ty * 4 + i];
#pragma unroll
      for (int j = 0; j < 4; ++j) b[j] = Bs[k][tx * 4 + j];
#pragma unroll
      for (int i = 0; i < 4; ++i)
#pragma unroll
        for (int j = 0; j < 4; ++j)
          acc[i][j] = fmaf(a[i], b[j], acc[i][j]);
    }
  }
#pragma unroll
  for (int i = 0; i < 4; ++i)
#pragma unroll
    for (int j = 0; j < 4; ++j)
      atomicAdd(&C[(size_t)(r0 + ty * 4 + i) * 64 + tx * 4 + j], acc[i][j]);
}

__global__ void k_bias_relu(float* __restrict__ X, const float* __restrict__ b) {
  int idx = blockIdx.x * 256 + threadIdx.x;
  int e = idx & 63;
  X[idx] = fmaxf(X[idx] + b[e], 0.f);
}

// P2[r,0:3] = X1[r,:] @ W2
__global__ void k_p2(const float* __restrict__ X1, const float* __restrict__ W2,
                     float* __restrict__ P2) {
  int r = blockIdx.x * 64 + threadIdx.x;
  float a0 = 0.f, a1 = 0.f, a2 = 0.f;
#pragma unroll 8
  for (int k = 0; k < 64; ++k) {
    float x = X1[(size_t)r * 64 + k];
    a0 = fmaf(x, W2[k * 3 + 0], a0);
    a1 = fmaf(x, W2[k * 3 + 1], a1);
    a2 = fmaf(x, W2[k * 3 + 2], a2);
  }
  P2[r * 4 + 0] = a0; P2[r * 4 + 1] = a1; P2[r * 4 + 2] = a2;
}

// logits[r,:] = log_softmax(adj[r,:] @ P2 + b2)
__global__ void k_out(const float* __restrict__ adj, const float* __restrict__ P2,
                      const float* __restrict__ b2, float* __restrict__ logits) {
  int r = blockIdx.x, t = threadIdx.x;  // 64 threads
  const float* arow = adj + (size_t)r * NT;
  float a0 = 0.f, a1 = 0.f, a2 = 0.f;
  for (int c = t; c < NT; c += 64) {
    float a = arow[c];
    a0 = fmaf(a, P2[c * 4 + 0], a0);
    a1 = fmaf(a, P2[c * 4 + 1], a1);
    a2 = fmaf(a, P2[c * 4 + 2], a2);
  }
  for (int off = 32; off; off >>= 1) {
    a0 += __shfl_xor(a0, off);
    a1 += __shfl_xor(a1, off);
    a2 += __shfl_xor(a2, off);
  }
  if (t == 0) {
    a0 += b2[0]; a1 += b2[1]; a2 += b2[2];
    float m = fmaxf(a0, fmaxf(a1, a2));
    float lse = m + logf(expf(a0 - m) + expf(a1 - m) + expf(a2 - m));
    logits[r * 3 + 0] = a0 - lse;
    logits[r * 3 + 1] = a1 - lse;
    logits[r * 3 + 2] = a2 - lse;
  }
}

// ---------------- host ----------------

extern "C" void kernel_launch(void* const* d_in, const int* in_sizes, int n_in,
                              void* d_out, int out_size, void* d_ws, size_t ws_size,
                              hipStream_t stream) {
  (void)in_sizes; (void)n_in; (void)out_size; (void)ws_size;
  const float* features = (const float*)d_in[0];
  const float* adj      = (const float*)d_in[1];
  const float* mp_pap   = (const float*)d_in[2];
  const float* mp_psp   = (const float*)d_in[3];
  const float* fgo_w    = (const float*)d_in[6];
  const float* fpo_w    = (const float*)d_in[7];
  const float* sgg_pap_w = (const float*)d_in[8];
  const float* sgg_psp_w = (const float*)d_in[9];
  const float* sg_agg_w  = (const float*)d_in[10];
  const float* f_agg_f_w = (const float*)d_in[11];
  const float* f_agg_w   = (const float*)d_in[12];
  const float* topo_W_a  = (const float*)d_in[13];
  const float* topo_b_a  = (const float*)d_in[14];
  const float* topo_W_s  = (const float*)d_in[15];
  const float* topo_b_s  = (const float*)d_in[16];
  const float* fgt_w_a   = (const float*)d_in[17];
  const float* fgt_w_s   = (const float*)d_in[18];
  const float* gcn_W1    = (const float*)d_in[19];
  const float* gcn_b1    = (const float*)d_in[20];
  const float* gcn_W2    = (const float*)d_in[21];
  const float* gcn_b2    = (const float*)d_in[22];

  float* logits = (float*)d_out;
  float* adjOut = (float*)d_out + (size_t)NT * 3;      // 4096x4096 f32 output
  bf16_t* simA  = (bf16_t*)adjOut;                     // scratch lifetime before combine

  float* ws = (float*)d_ws;
  size_t o = 0;
  bf16_t* Vg   = (bf16_t*)(ws + o); o += (size_t)NT * 128;   // NT x 256 bf16
  bf16_t* Vfa  = (bf16_t*)(ws + o); o += (size_t)NA * 128;
  bf16_t* Vf0  = (bf16_t*)(ws + o); o += (size_t)NT * 128;
  bf16_t* Vf1  = (bf16_t*)(ws + o); o += (size_t)NT * 128;
  bf16_t* Vpap = (bf16_t*)(ws + o); o += (size_t)NT * 64;    // NT x 128 bf16
  bf16_t* Vpsp = (bf16_t*)(ws + o); o += (size_t)NT * 64;
  bf16_t* Vs0  = (bf16_t*)(ws + o); o += (size_t)NT * 64;
  bf16_t* Vs1  = (bf16_t*)(ws + o); o += (size_t)NT * 64;
  bf16_t* Vfs  = (bf16_t*)(ws + o); o += (size_t)NS * 128;
  bf16_t* simS = (bf16_t*)(ws + o); o += (size_t)NS * NS / 2;
  bf16_t* WaT  = (bf16_t*)(ws + o); o += (size_t)64 * NA / 2;
  bf16_t* WsT  = (bf16_t*)(ws + o); o += (size_t)64 * NS / 2;
  float* fpa  = ws + o; o += (size_t)NT * 128;
  float* fps  = ws + o; o += (size_t)NT * 128;
  float* Sa   = ws + o; o += (size_t)NA * 64;   // zeroed (atomic target)
  float* Ss   = ws + o; o += (size_t)NS * 64;   // contiguous with Sa
  float* topoA = ws + o; o += (size_t)NT * 64;
  float* topoS = ws + o; o += (size_t)NT * 64;
  float* H1   = ws + o; o += (size_t)NT * 64;
  float* X1   = ws + o; o += (size_t)NT * 64;   // zeroed (atomic target)
  float* P2   = ws + o; o += (size_t)NT * 4;
  float* cs   = ws + o; o += (size_t)7 * NT;    // zeroed
  float* fcs  = ws + o; o += NT;                // contiguous with cs
  float* coef = ws + o; o += (size_t)7 * NT;
  float* w8   = ws + o; o += 8;

  hipMemsetAsync(cs, 0, (size_t)8 * NT * sizeof(float), stream);
  hipMemsetAsync(Sa, 0, (size_t)(NA + NS) * 64 * sizeof(float), stream);
  hipMemsetAsync(X1, 0, (size_t)NT * 64 * sizeof(float), stream);
  k_weights<<<1, 1, 0, stream>>>(sg_agg_w, f_agg_f_w, f_agg_w, w8);

  // normalized head-weighted feature vectors (bf16)
  k_rownorm<<<NT, 64, 0, stream>>>(features, 128, fgo_w, Vg);
  k_rownorm<<<NT, 64, 0, stream>>>(mp_pap, 64, sgg_pap_w, Vpap);
  k_rownorm<<<NT, 64, 0, stream>>>(mp_psp, 64, sgg_psp_w, Vpsp);
  k_rownorm<<<NA, 64, 0, stream>>>(features + (size_t)NT * 128, 128, fgo_w, Vfa);
  k_rownorm<<<NS, 64, 0, stream>>>(features + (size_t)(NT + NA) * 128, 128, fgo_w, Vfs);

  // feat_prop = ori_g @ fmat_r  (sparse ballot-scan)
  k_spmm128<<<NT, 128, 0, stream>>>(adj, NT, NA, features + (size_t)NT * 128, fpa);
  k_spmm128<<<NT, 128, 0, stream>>>(adj, NT + NA, NS, features + (size_t)(NT + NA) * 128, fps);
  k_rownorm<<<NT, 64, 0, stream>>>(fpa, 128, fpo_w, Vf0);
  k_rownorm<<<NT, 64, 0, stream>>>(fps, 128, fpo_w, Vf1);

  // topo weight transposes (bf16 rows)
  k_transp<<<(NA * 64) / 256, 256, 0, stream>>>(topo_W_a, NA, WaT);
  k_transp<<<(NS * 64) / 256, 256, 0, stream>>>(topo_W_s, NS, WsT);

  // sim_r (thresholded, bf16) and S_r = sim_r @ topo_W (MFMA split-K, atomic f32)
  k_gram_sim<<<dim3(NA / 128, NA / 128), 256, 0, stream>>>(Vfa, NA, 256, 0.1f, simA);
  k_gram_sim<<<dim3(NS / 128, NS / 128), 256, 0, stream>>>(Vfs, NS, 256, 0.1f, simS);
  k_gemmT<<<dim3(NA / 128, 8), 256, 0, stream>>>(simA, WaT, Sa, NA, NA / 8);
  k_gemmT<<<dim3(NS / 128, 8), 256, 0, stream>>>(simS, WsT, Ss, NS, NS / 8);

  // topo_hid = ori_g @ S_r + b
  k_spmm64<<<NT, 128, 0, stream>>>(adj, NT, NA, Sa, topo_b_a, topoA);
  k_spmm64<<<NT, 128, 0, stream>>>(adj, NT + NA, NS, Ss, topo_b_s, topoS);
  k_rownorm<<<NT, 64, 0, stream>>>(topoA, 64, fgt_w_a, Vs0);
  k_rownorm<<<NT, 64, 0, stream>>>(topoS, 64, fgt_w_s, Vs1);

  // pass 1: per-channel column sums (MFMA, spill-free) -> coefficients
  k_colsum_all<<<NBLK * NBLK, 512, 0, stream>>>(Vg, Vpap, Vpsp, Vf0, Vf1, Vs0, Vs1, cs);
  k_coef<<<NT / 256, 256, 0, stream>>>(cs, w8, coef);

  // pass 2: combine + symmetrize, triangle blocks + LDS-transposed mirror writes
  k_combine<<<(NBLK * (NBLK + 1)) / 2, 512, 0, stream>>>(Vg, Vpap, Vpsp, Vf0, Vf1, Vs0, Vs1,
                                                         coef, adjOut, fcs);
  k_scale<<<(NT * NT) / 256, 256, 0, stream>>>(adjOut, fcs);

  // GCN (f32 tail)
  k_gemm_n64<<<NT / 64, 256, 0, stream>>>(features, 128, gcn_W1, H1, nullptr, 0);
  k_gemm_n64_sk<<<dim3(NT / 64, 8), 256, 0, stream>>>(adjOut, NT, NT / 8, H1, X1);
  k_bias_relu<<<(NT * 64) / 256, 256, 0, stream>>>(X1, gcn_b1);
  k_p2<<<NT / 64, 64, 0, stream>>>(X1, gcn_W2, P2);
  k_out<<<NT, 64, 0, stream>>>(adjOut, P2, gcn_b2, logits);
}

// Round 5
// 1263.638 us; speedup vs baseline: 1.0549x; 1.0549x over previous
//
#include <hip/hip_runtime.h>
#include <math.h>

#define NT 4096
#define NA 4096
#define NS 1024
#define NALL 9216
#define NBLK 32   // NT/128

typedef __bf16 bf16_t;
typedef bf16_t bf16x8 __attribute__((ext_vector_type(8)));
typedef float f32x4 __attribute__((ext_vector_type(4)));

static __device__ __forceinline__ f32x4 mfma_bf16(bf16x8 a, bf16x8 b, f32x4 c) {
  return __builtin_amdgcn_mfma_f32_16x16x32_bf16(a, b, c, 0, 0, 0);
}

// ---------------- small prep kernels ----------------

__global__ void k_weights(const float* __restrict__ sg, const float* __restrict__ ff,
                          const float* __restrict__ f4, float* __restrict__ w8) {
  float m = fmaxf(sg[0], sg[1]);
  float e0 = expf(sg[0] - m), e1 = expf(sg[1] - m);
  w8[0] = e0 / (e0 + e1); w8[1] = e1 / (e0 + e1);
  m = fmaxf(ff[0], ff[1]);
  e0 = expf(ff[0] - m); e1 = expf(ff[1] - m);
  w8[2] = e0 / (e0 + e1); w8[3] = e1 / (e0 + e1);
  m = fmaxf(fmaxf(f4[0], f4[1]), fmaxf(f4[2], f4[3]));
  float a0 = expf(f4[0] - m), a1 = expf(f4[1] - m), a2 = expf(f4[2] - m), a3 = expf(f4[3] - m);
  float s = a0 + a1 + a2 + a3;
  w8[4] = a0 / s; w8[5] = a1 / s; w8[6] = a2 / s; w8[7] = a3 / s;
}

// V[r, h*D+d] = (src[r,d]*w[h,d]) / max(||src[r,:]*w[h,:]||, 1e-12), output bf16
__global__ void k_rownorm(const float* __restrict__ src, int D,
                          const float* __restrict__ w, bf16_t* __restrict__ V) {
  int r = blockIdx.x;
  int t = threadIdx.x;  // 64 threads = 1 wave
  const float* x = src + (size_t)r * D;
  bf16_t* out = V + (size_t)r * (2 * D);
  for (int h = 0; h < 2; ++h) {
    float ss = 0.f;
    for (int d = t; d < D; d += 64) {
      float y = x[d] * w[h * D + d];
      ss = fmaf(y, y, ss);
    }
    for (int off = 32; off; off >>= 1) ss += __shfl_xor(ss, off);
    float nrm = fmaxf(sqrtf(ss), 1e-12f);
    for (int d = t; d < D; d += 64) {
      float y = x[d] * w[h * D + d];
      out[h * D + d] = (bf16_t)(y / nrm);
    }
  }
}

// out[r,0:128] = sum_c adj[r, colbase+c] * feats[c, 0:128]   (adj ~0.5% dense; ballot scan)
__global__ void k_spmm128(const float* __restrict__ adj, int colbase, int ncols,
                          const float* __restrict__ feats, float* __restrict__ out) {
  int r = blockIdx.x, t = threadIdx.x, wv = t >> 6, lane = t & 63;  // 128 thr = 2 waves
  const float* arow = adj + (size_t)r * NALL + colbase;
  float acc0 = 0.f, acc1 = 0.f;
  for (int c0 = wv * 64; c0 < ncols; c0 += 128) {
    float a = arow[c0 + lane];
    unsigned long long m = __ballot(a != 0.f);
    while (m) {
      int b = __builtin_ctzll(m); m &= m - 1;
      float v = __shfl(a, b);
      const float* f = feats + (size_t)(c0 + b) * 128;
      acc0 = fmaf(v, f[lane], acc0);
      acc1 = fmaf(v, f[lane + 64], acc1);
    }
  }
  __shared__ float red[2][128];
  red[wv][lane] = acc0; red[wv][lane + 64] = acc1;
  __syncthreads();
  if (t < 128) out[(size_t)r * 128 + t] = red[0][t] + red[1][t];
}

// out[r,0:64] = sum_c adj[r, colbase+c] * S[c,0:64] + bias
__global__ void k_spmm64(const float* __restrict__ adj, int colbase, int ncols,
                         const float* __restrict__ S, const float* __restrict__ bias,
                         float* __restrict__ out) {
  int r = blockIdx.x, t = threadIdx.x, wv = t >> 6, lane = t & 63;  // 128 thr = 2 waves
  const float* arow = adj + (size_t)r * NALL + colbase;
  float acc = 0.f;
  for (int c0 = wv * 64; c0 < ncols; c0 += 128) {
    float a = arow[c0 + lane];
    unsigned long long m = __ballot(a != 0.f);
    while (m) {
      int b = __builtin_ctzll(m); m &= m - 1;
      float v = __shfl(a, b);
      acc = fmaf(v, S[(size_t)(c0 + b) * 64 + lane], acc);
    }
  }
  __shared__ float red[2][64];
  red[wv][lane] = acc;
  __syncthreads();
  if (t < 64) out[(size_t)r * 64 + t] = red[0][t] + red[1][t] + bias[t];
}

// Wt[n][k] = (bf16) W[k][n]   (W: [K][64] f32)
__global__ void k_transp(const float* __restrict__ W, int K, bf16_t* __restrict__ Wt) {
  int idx = blockIdx.x * 256 + threadIdx.x;
  int n = idx & 63, k = idx >> 6;
  if (k < K) Wt[(size_t)n * K + k] = (bf16_t)W[(size_t)k * 64 + n];
}

// ---------------- MFMA Gram tile core (all compile-time shapes) ----------------
// Wave computes (MF*16)x(NF*16) tile of V*V^T. Both operands loaded as ROWS of V with
// identical lane patterns (k-permutation invariance makes the A/B layout robust).

template <int K, int MF, int NF>
static __device__ __forceinline__ void gramMN(const bf16_t* __restrict__ V,
                                              int r0, int c0, int rq, int kq,
                                              f32x4 acc[MF][NF]) {
  const bf16_t* Ap = V + (size_t)(r0 + rq) * K + kq * 8;
  const bf16_t* Bp = V + (size_t)(c0 + rq) * K + kq * 8;
#pragma unroll
  for (int kc = 0; kc < K; kc += 32) {
    bf16x8 a[MF], b[NF];
#pragma unroll
    for (int f = 0; f < MF; ++f) a[f] = *(const bf16x8*)(Ap + (size_t)(f * 16) * K + kc);
#pragma unroll
    for (int f = 0; f < NF; ++f) b[f] = *(const bf16x8*)(Bp + (size_t)(f * 16) * K + kc);
#pragma unroll
    for (int fi = 0; fi < MF; ++fi)
#pragma unroll
      for (int fj = 0; fj < NF; ++fj)
        acc[fi][fj] = mfma_bf16(a[fi], b[fj], acc[fi][fj]);
  }
}

// sim[r,c] = thresh(0.5 * V[r].V[c]) -> bf16, row length R. 512 thr, wave tile 32x64.
__global__ __launch_bounds__(512, 4) void k_gram_sim(const bf16_t* __restrict__ V, int R, int K,
                                                     float th, bf16_t* __restrict__ out) {
  int tid = threadIdx.x, lane = tid & 63, w = tid >> 6;
  int wr = w >> 1, wc = w & 1, rq = lane & 15, kq = lane >> 4;
  int r0 = blockIdx.y * 128 + wr * 32, c0 = blockIdx.x * 128 + wc * 64;
  f32x4 acc[2][4];
#pragma unroll
  for (int i = 0; i < 2; ++i)
#pragma unroll
    for (int j = 0; j < 4; ++j) acc[i][j] = 0.f;
  if (K == 256) gramMN<256, 2, 4>(V, r0, c0, rq, kq, acc);
  else          gramMN<128, 2, 4>(V, r0, c0, rq, kq, acc);
#pragma unroll
  for (int fi = 0; fi < 2; ++fi)
#pragma unroll
    for (int fj = 0; fj < 4; ++fj)
#pragma unroll
      for (int reg = 0; reg < 4; ++reg) {
        float s = 0.5f * acc[fi][fj][reg];
        int row = r0 + fi * 16 + kq * 4 + reg;
        int col = c0 + fj * 16 + rq;
        out[(size_t)row * R + col] = (bf16_t)((s < th) ? 0.f : s);
      }
}

// ---- per-channel helpers (compile-time K, no runtime-indexed arrays anywhere) ----

template <int K>
static __device__ __forceinline__ void colsum_ch(const bf16_t* __restrict__ V, float th,
                                                 float* __restrict__ csch,
                                                 int r0, int c0, int rq, int kq, bool mirror) {
  f32x4 acc[2][2];
#pragma unroll
  for (int i = 0; i < 2; ++i)
#pragma unroll
    for (int j = 0; j < 2; ++j) acc[i][j] = 0.f;
  gramMN<K, 2, 2>(V, r0, c0, rq, kq, acc);
  float part[2] = {0.f, 0.f};
  float rp[2][4] = {};
#pragma unroll
  for (int fi = 0; fi < 2; ++fi)
#pragma unroll
    for (int fj = 0; fj < 2; ++fj)
#pragma unroll
      for (int reg = 0; reg < 4; ++reg) {
        float s = 0.5f * acc[fi][fj][reg];
        if (s >= th) { part[fj] += s; rp[fi][reg] += s; }
      }
#pragma unroll
  for (int fj = 0; fj < 2; ++fj) {
    float p = part[fj];
    p += __shfl_xor(p, 16);
    p += __shfl_xor(p, 32);
    if (kq == 0) atomicAdd(&csch[c0 + fj * 16 + rq], p);
  }
  if (mirror) {
#pragma unroll
    for (int fi = 0; fi < 2; ++fi)
#pragma unroll
      for (int reg = 0; reg < 4; ++reg) {
        float r = rp[fi][reg];
        r += __shfl_xor(r, 1); r += __shfl_xor(r, 2);
        r += __shfl_xor(r, 4); r += __shfl_xor(r, 8);
        if (rq == 0) atomicAdd(&csch[r0 + fi * 16 + kq * 4 + reg], r);
      }
  }
}

template <int K>
static __device__ __forceinline__ void combine_ch(const bf16_t* __restrict__ V,
                                                  const float* __restrict__ cf, float th,
                                                  int r0, int c0, int rq, int kq,
                                                  f32x4 comb[2][2]) {
  f32x4 acc[2][2];
#pragma unroll
  for (int i = 0; i < 2; ++i)
#pragma unroll
    for (int j = 0; j < 2; ++j) acc[i][j] = 0.f;
  gramMN<K, 2, 2>(V, r0, c0, rq, kq, acc);
  float cc0 = cf[c0 + rq], cc1 = cf[c0 + 16 + rq];
#pragma unroll
  for (int fi = 0; fi < 2; ++fi) {
    f32x4 cr = *(const f32x4*)&cf[r0 + fi * 16 + kq * 4];
#pragma unroll
    for (int fj = 0; fj < 2; ++fj) {
      float cc_ = fj ? cc1 : cc0;
#pragma unroll
      for (int reg = 0; reg < 4; ++reg) {
        float s = 0.5f * acc[fi][fj][reg];
        if (s >= th) comb[fi][fj][reg] = fmaf(cr[reg] + cc_, s, comb[fi][fj][reg]);
      }
    }
  }
}

// triangle decode with XCD swizzle (528 blocks; 528 % 8 == 0)
static __device__ __forceinline__ void tri_decode(int flat, int& bi, int& bj) {
  int swz = (flat & 7) * 66 + (flat >> 3);
  int b = 0, rem = swz;
  while (rem >= NBLK - b) { rem -= NBLK - b; ++b; }
  bi = b; bj = b + rem;
}

// all-7-channel thresholded column sums -> cs[7][NT]; triangle blocks, mirror row-sums
__global__ __launch_bounds__(1024, 4) void k_colsum_all(
    const bf16_t* __restrict__ Vg, const bf16_t* __restrict__ Vpap, const bf16_t* __restrict__ Vpsp,
    const bf16_t* __restrict__ Vf0, const bf16_t* __restrict__ Vf1,
    const bf16_t* __restrict__ Vs0, const bf16_t* __restrict__ Vs1,
    float* __restrict__ cs) {
  int tid = threadIdx.x, lane = tid & 63, w = tid >> 6;
  int wr = w >> 2, wc = w & 3, rq = lane & 15, kq = lane >> 4;
  int bi, bj; tri_decode(blockIdx.x, bi, bj);
  int r0 = bi * 128 + wr * 32, c0 = bj * 128 + wc * 32;
  bool mir = (bi != bj);
  colsum_ch<256>(Vg,   0.1f, cs + 0 * NT, r0, c0, rq, kq, mir);
  colsum_ch<128>(Vpap, 0.1f, cs + 1 * NT, r0, c0, rq, kq, mir);
  colsum_ch<128>(Vpsp, 0.1f, cs + 2 * NT, r0, c0, rq, kq, mir);
  colsum_ch<256>(Vf0,  0.2f, cs + 3 * NT, r0, c0, rq, kq, mir);
  colsum_ch<256>(Vf1,  0.2f, cs + 4 * NT, r0, c0, rq, kq, mir);
  colsum_ch<128>(Vs0,  0.1f, cs + 5 * NT, r0, c0, rq, kq, mir);
  colsum_ch<128>(Vs1,  0.1f, cs + 6 * NT, r0, c0, rq, kq, mir);
}

// per-column combine coefficients from colsums + softmaxed agg weights
__global__ void k_coef(const float* __restrict__ cs, const float* __restrict__ w8,
                       float* __restrict__ coef) {
  int c = blockIdx.x * 256 + threadIdx.x;
  if (c >= NT) return;
  float csg = cs[c], cspap = cs[NT + c], cspsp = cs[2 * NT + c];
  float csf0 = cs[3 * NT + c], csf1 = cs[4 * NT + c];
  float css0 = cs[5 * NT + c], css1 = cs[6 * NT + c];
  float wS0 = w8[0], wS1 = w8[1], wFF0 = w8[2], wFF1 = w8[3];
  float wF0 = w8[4], wF1 = w8[5], wF2 = w8[6], wF3 = w8[7];
  auto mx = [](float x) { return fmaxf(x, 1e-12f); };
  auto ind = [](float x) { return x > 0.f ? 1.f : 0.f; };
  float cssem = wS0 * ind(cspap) + wS1 * ind(cspsp);
  float csfp = wFF0 * ind(csf0) + wFF1 * ind(csf1);
  float cstt = wFF0 * ind(css0) + wFF1 * ind(css1);
  coef[c]          = wF0 / mx(csg);
  coef[NT + c]     = wF1 * wS0 / (mx(cspap) * mx(cssem));
  coef[2 * NT + c] = wF1 * wS1 / (mx(cspsp) * mx(cssem));
  coef[3 * NT + c] = wF2 * wFF0 / (mx(csf0) * mx(csfp));
  coef[4 * NT + c] = wF2 * wFF1 / (mx(csf1) * mx(csfp));
  coef[5 * NT + c] = wF3 * wFF0 / (mx(css0) * mx(cstt));
  coef[6 * NT + c] = wF3 * wFF1 / (mx(css1) * mx(cstt));
}

// sym[r,c] = sum_ch (coef[r]+coef[c]) * M_ch[r,c]; triangle blocks; mirror via per-wave
// LDS transpose; finalcs gets col sums (direct) + row sums (mirror columns).
__global__ __launch_bounds__(1024, 4) void k_combine(
    const bf16_t* __restrict__ Vg, const bf16_t* __restrict__ Vpap, const bf16_t* __restrict__ Vpsp,
    const bf16_t* __restrict__ Vf0, const bf16_t* __restrict__ Vf1,
    const bf16_t* __restrict__ Vs0, const bf16_t* __restrict__ Vs1,
    const float* __restrict__ coef, float* __restrict__ outAdj, float* __restrict__ finalcs) {
  __shared__ float ldsT[16][32 * 32];  // 64 KiB: per-wave 32x32 transpose scratch
  int tid = threadIdx.x, lane = tid & 63, w = tid >> 6;
  int wr = w >> 2, wc = w & 3, rq = lane & 15, kq = lane >> 4;
  int bi, bj; tri_decode(blockIdx.x, bi, bj);
  int r0 = bi * 128 + wr * 32, c0 = bj * 128 + wc * 32;
  f32x4 comb[2][2];
#pragma unroll
  for (int i = 0; i < 2; ++i)
#pragma unroll
    for (int j = 0; j < 2; ++j) comb[i][j] = 0.f;
  combine_ch<256>(Vg,   coef + 0 * NT, 0.1f, r0, c0, rq, kq, comb);
  combine_ch<128>(Vpap, coef + 1 * NT, 0.1f, r0, c0, rq, kq, comb);
  combine_ch<128>(Vpsp, coef + 2 * NT, 0.1f, r0, c0, rq, kq, comb);
  combine_ch<256>(Vf0,  coef + 3 * NT, 0.2f, r0, c0, rq, kq, comb);
  combine_ch<256>(Vf1,  coef + 4 * NT, 0.2f, r0, c0, rq, kq, comb);
  combine_ch<128>(Vs0,  coef + 5 * NT, 0.1f, r0, c0, rq, kq, comb);
  combine_ch<128>(Vs1,  coef + 6 * NT, 0.1f, r0, c0, rq, kq, comb);

  // direct write + column partial sums
  float part[2] = {0.f, 0.f};
#pragma unroll
  for (int fi = 0; fi < 2; ++fi)
#pragma unroll
    for (int fj = 0; fj < 2; ++fj)
#pragma unroll
      for (int reg = 0; reg < 4; ++reg) {
        float v = comb[fi][fj][reg];
        int row = r0 + fi * 16 + kq * 4 + reg;
        int col = c0 + fj * 16 + rq;
        outAdj[(size_t)row * NT + col] = v;
        part[fj] += v;
      }
#pragma unroll
  for (int fj = 0; fj < 2; ++fj) {
    float p = part[fj];
    p += __shfl_xor(p, 16);
    p += __shfl_xor(p, 32);
    if (kq == 0) atomicAdd(&finalcs[c0 + fj * 16 + rq], p);
  }

  if (bi != bj) {
    // mirror write via per-wave LDS transpose (XOR-swizzled)
    float* T = ldsT[w];
#pragma unroll
    for (int fi = 0; fi < 2; ++fi)
#pragma unroll
      for (int fj = 0; fj < 2; ++fj)
#pragma unroll
        for (int reg = 0; reg < 4; ++reg) {
          int r = fi * 16 + kq * 4 + reg;  // local row [0,32)
          int c = fj * 16 + rq;            // local col [0,32)
          T[c * 32 + (r ^ ((c & 15) << 1))] = comb[fi][fj][reg];
        }
    int hl = lane >> 5, l32 = lane & 31;
    float rsum = 0.f;
#pragma unroll
    for (int cc = 0; cc < 16; ++cc) {
      int c = cc * 2 + hl;
      float v = T[c * 32 + (l32 ^ ((c & 15) << 1))];
      rsum += v;
      outAdj[(size_t)(c0 + c) * NT + r0 + l32] = v;
    }
    rsum += __shfl_xor(rsum, 32);
    if (lane < 32) atomicAdd(&finalcs[r0 + l32], rsum);
  }
}

__global__ void k_scale(float* __restrict__ adj, const float* __restrict__ finalcs) {
  size_t idx = (size_t)blockIdx.x * 256 + threadIdx.x;
  int c = (int)(idx & (NT - 1));
  adj[idx] = adj[idx] / fmaxf(finalcs[c], 1e-12f);
}

// C[M][64] (f32, atomic) += Arows(bf16 [M][K]) . Brows(bf16 [64][K]) over K-chunk
__global__ __launch_bounds__(256, 2) void k_gemmT(const bf16_t* __restrict__ A,
                                                  const bf16_t* __restrict__ Bt,
                                                  float* __restrict__ C, int K, int kchunk) {
  int tid = threadIdx.x, lane = tid & 63, w = tid >> 6;
  int rq = lane & 15, kq = lane >> 4;
  int r0 = blockIdx.x * 128 + w * 32;
  int kb = blockIdx.y * kchunk;
  f32x4 acc[2][4];
#pragma unroll
  for (int i = 0; i < 2; ++i)
#pragma unroll
    for (int j = 0; j < 4; ++j) acc[i][j] = 0.f;
  const bf16_t* Ap = A + (size_t)(r0 + rq) * K + kb + kq * 8;
  const bf16_t* Bp = Bt + (size_t)rq * K + kb + kq * 8;
#pragma unroll 2
  for (int kc = 0; kc < kchunk; kc += 32) {
    bf16x8 a[2], b[4];
#pragma unroll
    for (int f = 0; f < 2; ++f) a[f] = *(const bf16x8*)(Ap + (size_t)(f * 16) * K + kc);
#pragma unroll
    for (int f = 0; f < 4; ++f) b[f] = *(const bf16x8*)(Bp + (size_t)(f * 16) * K + kc);
#pragma unroll
    for (int fi = 0; fi < 2; ++fi)
#pragma unroll
      for (int fj = 0; fj < 4; ++fj)
        acc[fi][fj] = mfma_bf16(a[fi], b[fj], acc[fi][fj]);
  }
#pragma unroll
  for (int fi = 0; fi < 2; ++fi)
#pragma unroll
    for (int fj = 0; fj < 4; ++fj)
#pragma unroll
      for (int reg = 0; reg < 4; ++reg) {
        int row = r0 + fi * 16 + kq * 4 + reg;
        int col = fj * 16 + rq;
        atomicAdd(&C[(size_t)row * 64 + col], acc[fi][fj][reg]);
      }
}

// ---------------- f32 tile GEMMs (precision-sensitive tail) ----------------

__global__ __launch_bounds__(256) void k_gemm_n64(const float* __restrict__ A, int K,
                                                  const float* __restrict__ B,
                                                  float* __restrict__ C,
                                                  const float* __restrict__ bias, int relu) {
  __shared__ float As[64][68], Bs[64][68];
  int r0 = blockIdx.x * 64;
  int tid = threadIdx.x, tx = tid & 15, ty = tid >> 4;
  float acc[4][4] = {};
  for (int kc = 0; kc < K; kc += 64) {
    __syncthreads();
#pragma unroll
    for (int m = 0; m < 16; ++m) {
      int lin = tid + 256 * m;
      int row = lin >> 6, col = lin & 63;
      As[col][row] = A[(size_t)(r0 + row) * K + kc + col];
      Bs[row][col] = B[(size_t)(kc + row) * 64 + col];
    }
    __syncthreads();
#pragma unroll 8
    for (int k = 0; k < 64; ++k) {
      float a[4], b[4];
#pragma unroll
      for (int i = 0; i < 4; ++i) a[i] = As[k][ty * 4 + i];
#pragma unroll
      for (int j = 0; j < 4; ++j) b[j] = Bs[k][tx * 4 + j];
#pragma unroll
      for (int i = 0; i < 4; ++i)
#pragma unroll
        for (int j = 0; j < 4; ++j)
          acc[i][j] = fmaf(a[i], b[j], acc[i][j]);
    }
  }
#pragma unroll
  for (int i = 0; i < 4; ++i)
#pragma unroll
    for (int j = 0; j < 4; ++j) {
      float v = acc[i][j];
      if (bias) v += bias[tx * 4 + j];
      if (relu) v = fmaxf(v, 0.f);
      C[(size_t)(r0 + ty * 4 + i) * 64 + tx * 4 + j] = v;
    }
}

// split-K f32: C[M][64] += A[M][K-chunk] @ B[K][64]  (atomic)
__global__ __launch_bounds__(256) void k_gemm_n64_sk(const float* __restrict__ A, int K,
                                                     int kchunk, const float* __restrict__ B,
                                                     float* __restrict__ C) {
  __shared__ float As[64][68], Bs[64][68];
  int r0 = blockIdx.x * 64;
  int kb = blockIdx.y * kchunk;
  int tid = threadIdx.x, tx = tid & 15, ty = tid >> 4;
  float acc[4][4] = {};
  for (int kc = kb; kc < kb + kchunk; kc += 64) {
    __syncthreads();
#pragma unroll
    for (int m = 0; m < 16; ++m) {
      int lin = tid + 256 * m;
      int row = lin >> 6, col = lin & 63;
      As[col][row] = A[(size_t)(r0 + row) * K + kc + col];
      Bs[row][col] = B[(size_t)(kc + row) * 64 + col];
    }
    __syncthreads();
#pragma unroll 8
    for (int k = 0; k < 64; ++k) {
      float a[4], b[4];
#pragma unroll
      for (int i = 0; i < 4; ++i) a[i] = As[k][ty * 4 + i];
#pragma unroll
      for (int j = 0; j < 4; ++j) b[j] = Bs[k][tx * 4 + j];
#pragma unroll
      for (int i = 0; i < 4; ++i)
#pragma unroll
        for (int j = 0; j < 4; ++j)
          acc[i][j] = fmaf(a[i], b[j], acc[i][j]);
    }
  }
#pragma unroll
  for (int i = 0; i < 4; ++i)
#pragma unroll
    for (int j = 0; j < 4; ++j)
      atomicAdd(&C[(size_t)(r0 + ty * 4 + i) * 64 + tx * 4 + j], acc[i][j]);
}

__global__ void k_bias_relu(float* __restrict__ X, const float* __restrict__ b) {
  int idx = blockIdx.x * 256 + threadIdx.x;
  int e = idx & 63;
  X[idx] = fmaxf(X[idx] + b[e], 0.f);
}

// P2[r,0:3] = X1[r,:] @ W2
__global__ void k_p2(const float* __restrict__ X1, const float* __restrict__ W2,
                     float* __restrict__ P2) {
  int r = blockIdx.x * 64 + threadIdx.x;
  float a0 = 0.f, a1 = 0.f, a2 = 0.f;
#pragma unroll 8
  for (int k = 0; k < 64; ++k) {
    float x = X1[(size_t)r * 64 + k];
    a0 = fmaf(x, W2[k * 3 + 0], a0);
    a1 = fmaf(x, W2[k * 3 + 1], a1);
    a2 = fmaf(x, W2[k * 3 + 2], a2);
  }
  P2[r * 4 + 0] = a0; P2[r * 4 + 1] = a1; P2[r * 4 + 2] = a2;
}

// logits[r,:] = log_softmax(adj[r,:] @ P2 + b2)
__global__ void k_out(const float* __restrict__ adj, const float* __restrict__ P2,
                      const float* __restrict__ b2, float* __restrict__ logits) {
  int r = blockIdx.x, t = threadIdx.x;  // 64 threads
  const float* arow = adj + (size_t)r * NT;
  float a0 = 0.f, a1 = 0.f, a2 = 0.f;
  for (int c = t; c < NT; c += 64) {
    float a = arow[c];
    a0 = fmaf(a, P2[c * 4 + 0], a0);
    a1 = fmaf(a, P2[c * 4 + 1], a1);
    a2 = fmaf(a, P2[c * 4 + 2], a2);
  }
  for (int off = 32; off; off >>= 1) {
    a0 += __shfl_xor(a0, off);
    a1 += __shfl_xor(a1, off);
    a2 += __shfl_xor(a2, off);
  }
  if (t == 0) {
    a0 += b2[0]; a1 += b2[1]; a2 += b2[2];
    float m = fmaxf(a0, fmaxf(a1, a2));
    float lse = m + logf(expf(a0 - m) + expf(a1 - m) + expf(a2 - m));
    logits[r * 3 + 0] = a0 - lse;
    logits[r * 3 + 1] = a1 - lse;
    logits[r * 3 + 2] = a2 - lse;
  }
}

// ---------------- host ----------------

extern "C" void kernel_launch(void* const* d_in, const int* in_sizes, int n_in,
                              void* d_out, int out_size, void* d_ws, size_t ws_size,
                              hipStream_t stream) {
  (void)in_sizes; (void)n_in; (void)out_size; (void)ws_size;
  const float* features = (const float*)d_in[0];
  const float* adj      = (const float*)d_in[1];
  const float* mp_pap   = (const float*)d_in[2];
  const float* mp_psp   = (const float*)d_in[3];
  const float* fgo_w    = (const float*)d_in[6];
  const float* fpo_w    = (const float*)d_in[7];
  const float* sgg_pap_w = (const float*)d_in[8];
  const float* sgg_psp_w = (const float*)d_in[9];
  const float* sg_agg_w  = (const float*)d_in[10];
  const float* f_agg_f_w = (const float*)d_in[11];
  const float* f_agg_w   = (const float*)d_in[12];
  const float* topo_W_a  = (const float*)d_in[13];
  const float* topo_b_a  = (const float*)d_in[14];
  const float* topo_W_s  = (const float*)d_in[15];
  const float* topo_b_s  = (const float*)d_in[16];
  const float* fgt_w_a   = (const float*)d_in[17];
  const float* fgt_w_s   = (const float*)d_in[18];
  const float* gcn_W1    = (const float*)d_in[19];
  const float* gcn_b1    = (const float*)d_in[20];
  const float* gcn_W2    = (const float*)d_in[21];
  const float* gcn_b2    = (const float*)d_in[22];

  float* logits = (float*)d_out;
  float* adjOut = (float*)d_out + (size_t)NT * 3;      // 4096x4096 f32 output
  bf16_t* simA  = (bf16_t*)adjOut;                     // scratch lifetime before combine

  float* ws = (float*)d_ws;
  size_t o = 0;
  bf16_t* Vg   = (bf16_t*)(ws + o); o += (size_t)NT * 128;   // NT x 256 bf16
  bf16_t* Vfa  = (bf16_t*)(ws + o); o += (size_t)NA * 128;
  bf16_t* Vf0  = (bf16_t*)(ws + o); o += (size_t)NT * 128;
  bf16_t* Vf1  = (bf16_t*)(ws + o); o += (size_t)NT * 128;
  bf16_t* Vpap = (bf16_t*)(ws + o); o += (size_t)NT * 64;    // NT x 128 bf16
  bf16_t* Vpsp = (bf16_t*)(ws + o); o += (size_t)NT * 64;
  bf16_t* Vs0  = (bf16_t*)(ws + o); o += (size_t)NT * 64;
  bf16_t* Vs1  = (bf16_t*)(ws + o); o += (size_t)NT * 64;
  bf16_t* Vfs  = (bf16_t*)(ws + o); o += (size_t)NS * 128;
  bf16_t* simS = (bf16_t*)(ws + o); o += (size_t)NS * NS / 2;
  bf16_t* WaT  = (bf16_t*)(ws + o); o += (size_t)64 * NA / 2;
  bf16_t* WsT  = (bf16_t*)(ws + o); o += (size_t)64 * NS / 2;
  float* fpa  = ws + o; o += (size_t)NT * 128;
  float* fps  = ws + o; o += (size_t)NT * 128;
  float* Sa   = ws + o; o += (size_t)NA * 64;   // zeroed (atomic target)
  float* Ss   = ws + o; o += (size_t)NS * 64;   // contiguous with Sa
  float* topoA = ws + o; o += (size_t)NT * 64;
  float* topoS = ws + o; o += (size_t)NT * 64;
  float* H1   = ws + o; o += (size_t)NT * 64;
  float* X1   = ws + o; o += (size_t)NT * 64;   // zeroed (atomic target)
  float* P2   = ws + o; o += (size_t)NT * 4;
  float* cs   = ws + o; o += (size_t)7 * NT;    // zeroed
  float* fcs  = ws + o; o += NT;                // contiguous with cs
  float* coef = ws + o; o += (size_t)7 * NT;
  float* w8   = ws + o; o += 8;

  hipMemsetAsync(cs, 0, (size_t)8 * NT * sizeof(float), stream);
  hipMemsetAsync(Sa, 0, (size_t)(NA + NS) * 64 * sizeof(float), stream);
  hipMemsetAsync(X1, 0, (size_t)NT * 64 * sizeof(float), stream);
  k_weights<<<1, 1, 0, stream>>>(sg_agg_w, f_agg_f_w, f_agg_w, w8);

  // normalized head-weighted feature vectors (bf16)
  k_rownorm<<<NT, 64, 0, stream>>>(features, 128, fgo_w, Vg);
  k_rownorm<<<NT, 64, 0, stream>>>(mp_pap, 64, sgg_pap_w, Vpap);
  k_rownorm<<<NT, 64, 0, stream>>>(mp_psp, 64, sgg_psp_w, Vpsp);
  k_rownorm<<<NA, 64, 0, stream>>>(features + (size_t)NT * 128, 128, fgo_w, Vfa);
  k_rownorm<<<NS, 64, 0, stream>>>(features + (size_t)(NT + NA) * 128, 128, fgo_w, Vfs);

  // feat_prop = ori_g @ fmat_r  (sparse ballot-scan)
  k_spmm128<<<NT, 128, 0, stream>>>(adj, NT, NA, features + (size_t)NT * 128, fpa);
  k_spmm128<<<NT, 128, 0, stream>>>(adj, NT + NA, NS, features + (size_t)(NT + NA) * 128, fps);
  k_rownorm<<<NT, 64, 0, stream>>>(fpa, 128, fpo_w, Vf0);
  k_rownorm<<<NT, 64, 0, stream>>>(fps, 128, fpo_w, Vf1);

  // topo weight transposes (bf16 rows)
  k_transp<<<(NA * 64) / 256, 256, 0, stream>>>(topo_W_a, NA, WaT);
  k_transp<<<(NS * 64) / 256, 256, 0, stream>>>(topo_W_s, NS, WsT);

  // sim_r (thresholded, bf16) and S_r = sim_r @ topo_W (MFMA split-K, atomic f32)
  k_gram_sim<<<dim3(NA / 128, NA / 128), 512, 0, stream>>>(Vfa, NA, 256, 0.1f, simA);
  k_gram_sim<<<dim3(NS / 128, NS / 128), 512, 0, stream>>>(Vfs, NS, 256, 0.1f, simS);
  k_gemmT<<<dim3(NA / 128, 8), 256, 0, stream>>>(simA, WaT, Sa, NA, NA / 8);
  k_gemmT<<<dim3(NS / 128, 8), 256, 0, stream>>>(simS, WsT, Ss, NS, NS / 8);

  // topo_hid = ori_g @ S_r + b
  k_spmm64<<<NT, 128, 0, stream>>>(adj, NT, NA, Sa, topo_b_a, topoA);
  k_spmm64<<<NT, 128, 0, stream>>>(adj, NT + NA, NS, Ss, topo_b_s, topoS);
  k_rownorm<<<NT, 64, 0, stream>>>(topoA, 64, fgt_w_a, Vs0);
  k_rownorm<<<NT, 64, 0, stream>>>(topoS, 64, fgt_w_s, Vs1);

  // pass 1: per-channel column sums (triangle + mirror row-sums) -> coefficients
  k_colsum_all<<<(NBLK * (NBLK + 1)) / 2, 1024, 0, stream>>>(Vg, Vpap, Vpsp, Vf0, Vf1, Vs0, Vs1, cs);
  k_coef<<<NT / 256, 256, 0, stream>>>(cs, w8, coef);

  // pass 2: combine + symmetrize, triangle blocks + LDS-transposed mirror writes
  k_combine<<<(NBLK * (NBLK + 1)) / 2, 1024, 0, stream>>>(Vg, Vpap, Vpsp, Vf0, Vf1, Vs0, Vs1,
                                                          coef, adjOut, fcs);
  k_scale<<<(NT * NT) / 256, 256, 0, stream>>>(adjOut, fcs);

  // GCN (f32 tail)
  k_gemm_n64<<<NT / 64, 256, 0, stream>>>(features, 128, gcn_W1, H1, nullptr, 0);
  k_gemm_n64_sk<<<dim3(NT / 64, 8), 256, 0, stream>>>(adjOut, NT, NT / 8, H1, X1);
  k_bias_relu<<<(NT * 64) / 256, 256, 0, stream>>>(X1, gcn_b1);
  k_p2<<<NT / 64, 64, 0, stream>>>(X1, gcn_W2, P2);
  k_out<<<NT, 64, 0, stream>>>(adjOut, P2, gcn_b2, logits);
}

// Round 6
// 1184.955 us; speedup vs baseline: 1.1250x; 1.0664x over previous
//
#include <hip/hip_runtime.h>
#include <math.h>

#define NT 4096
#define NA 4096
#define NS 1024
#define NALL 9216
#define NBLK 32   // NT/128

typedef __bf16 bf16_t;
typedef bf16_t bf16x8 __attribute__((ext_vector_type(8)));
typedef float f32x4 __attribute__((ext_vector_type(4)));

static __device__ __forceinline__ f32x4 mfma_bf16(bf16x8 a, bf16x8 b, f32x4 c) {
  return __builtin_amdgcn_mfma_f32_16x16x32_bf16(a, b, c, 0, 0, 0);
}

// ---------------- small prep kernels ----------------

__global__ void k_weights(const float* __restrict__ sg, const float* __restrict__ ff,
                          const float* __restrict__ f4, float* __restrict__ w8) {
  float m = fmaxf(sg[0], sg[1]);
  float e0 = expf(sg[0] - m), e1 = expf(sg[1] - m);
  w8[0] = e0 / (e0 + e1); w8[1] = e1 / (e0 + e1);
  m = fmaxf(ff[0], ff[1]);
  e0 = expf(ff[0] - m); e1 = expf(ff[1] - m);
  w8[2] = e0 / (e0 + e1); w8[3] = e1 / (e0 + e1);
  m = fmaxf(fmaxf(f4[0], f4[1]), fmaxf(f4[2], f4[3]));
  float a0 = expf(f4[0] - m), a1 = expf(f4[1] - m), a2 = expf(f4[2] - m), a3 = expf(f4[3] - m);
  float s = a0 + a1 + a2 + a3;
  w8[4] = a0 / s; w8[5] = a1 / s; w8[6] = a2 / s; w8[7] = a3 / s;
}

// V[r, h*D+d] = (src[r,d]*w[h,d]) / max(||src[r,:]*w[h,:]||, 1e-12), output bf16
__global__ void k_rownorm(const float* __restrict__ src, int D,
                          const float* __restrict__ w, bf16_t* __restrict__ V) {
  int r = blockIdx.x;
  int t = threadIdx.x;  // 64 threads = 1 wave
  const float* x = src + (size_t)r * D;
  bf16_t* out = V + (size_t)r * (2 * D);
  for (int h = 0; h < 2; ++h) {
    float ss = 0.f;
    for (int d = t; d < D; d += 64) {
      float y = x[d] * w[h * D + d];
      ss = fmaf(y, y, ss);
    }
    for (int off = 32; off; off >>= 1) ss += __shfl_xor(ss, off);
    float nrm = fmaxf(sqrtf(ss), 1e-12f);
    for (int d = t; d < D; d += 64) {
      float y = x[d] * w[h * D + d];
      out[h * D + d] = (bf16_t)(y / nrm);
    }
  }
}

// out[r,0:128] = sum_c adj[r, colbase+c] * feats[c, 0:128]   (adj ~0.5% dense; ballot scan)
__global__ void k_spmm128(const float* __restrict__ adj, int colbase, int ncols,
                          const float* __restrict__ feats, float* __restrict__ out) {
  int r = blockIdx.x, t = threadIdx.x, wv = t >> 6, lane = t & 63;  // 128 thr = 2 waves
  const float* arow = adj + (size_t)r * NALL + colbase;
  float acc0 = 0.f, acc1 = 0.f;
  for (int c0 = wv * 64; c0 < ncols; c0 += 128) {
    float a = arow[c0 + lane];
    unsigned long long m = __ballot(a != 0.f);
    while (m) {
      int b = __builtin_ctzll(m); m &= m - 1;
      float v = __shfl(a, b);
      const float* f = feats + (size_t)(c0 + b) * 128;
      acc0 = fmaf(v, f[lane], acc0);
      acc1 = fmaf(v, f[lane + 64], acc1);
    }
  }
  __shared__ float red[2][128];
  red[wv][lane] = acc0; red[wv][lane + 64] = acc1;
  __syncthreads();
  if (t < 128) out[(size_t)r * 128 + t] = red[0][t] + red[1][t];
}

// out[r,0:64] = sum_c adj[r, colbase+c] * S[c,0:64] + bias
__global__ void k_spmm64(const float* __restrict__ adj, int colbase, int ncols,
                         const float* __restrict__ S, const float* __restrict__ bias,
                         float* __restrict__ out) {
  int r = blockIdx.x, t = threadIdx.x, wv = t >> 6, lane = t & 63;  // 128 thr = 2 waves
  const float* arow = adj + (size_t)r * NALL + colbase;
  float acc = 0.f;
  for (int c0 = wv * 64; c0 < ncols; c0 += 128) {
    float a = arow[c0 + lane];
    unsigned long long m = __ballot(a != 0.f);
    while (m) {
      int b = __builtin_ctzll(m); m &= m - 1;
      float v = __shfl(a, b);
      acc = fmaf(v, S[(size_t)(c0 + b) * 64 + lane], acc);
    }
  }
  __shared__ float red[2][64];
  red[wv][lane] = acc;
  __syncthreads();
  if (t < 64) out[(size_t)r * 64 + t] = red[0][t] + red[1][t] + bias[t];
}

// Wt[n][k] = (bf16) W[k][n]   (W: [K][64] f32)
__global__ void k_transp(const float* __restrict__ W, int K, bf16_t* __restrict__ Wt) {
  int idx = blockIdx.x * 256 + threadIdx.x;
  int n = idx & 63, k = idx >> 6;
  if (k < K) Wt[(size_t)n * K + k] = (bf16_t)W[(size_t)k * 64 + n];
}

// ---------------- MFMA Gram tile core (reg-double-buffered, compile-time K) ------
// Wave computes (MF*16)x(NF*16) tile of V*V^T. Both operands loaded as ROWS of V with
// identical lane patterns (k-permutation invariance makes the A/B layout robust).
// Explicit 2-stage pipeline: loads for step t+1 issue before MFMAs of step t.

template <int K, int MF, int NF>
static __device__ __forceinline__ void gramMN(const bf16_t* __restrict__ V,
                                              int r0, int c0, int rq, int kq,
                                              f32x4 acc[MF][NF]) {
  const bf16_t* Ap = V + (size_t)(r0 + rq) * K + kq * 8;
  const bf16_t* Bp = V + (size_t)(c0 + rq) * K + kq * 8;
  bf16x8 a[MF], b[NF], a2[MF], b2[NF];
#pragma unroll
  for (int f = 0; f < MF; ++f) a[f] = *(const bf16x8*)(Ap + (size_t)(f * 16) * K);
#pragma unroll
  for (int f = 0; f < NF; ++f) b[f] = *(const bf16x8*)(Bp + (size_t)(f * 16) * K);
#pragma unroll
  for (int kc = 0; kc < K; kc += 32) {
    if (kc + 32 < K) {
#pragma unroll
      for (int f = 0; f < MF; ++f) a2[f] = *(const bf16x8*)(Ap + (size_t)(f * 16) * K + kc + 32);
#pragma unroll
      for (int f = 0; f < NF; ++f) b2[f] = *(const bf16x8*)(Bp + (size_t)(f * 16) * K + kc + 32);
    }
#pragma unroll
    for (int fi = 0; fi < MF; ++fi)
#pragma unroll
      for (int fj = 0; fj < NF; ++fj)
        acc[fi][fj] = mfma_bf16(a[fi], b[fj], acc[fi][fj]);
#pragma unroll
    for (int f = 0; f < MF; ++f) a[f] = a2[f];
#pragma unroll
    for (int f = 0; f < NF; ++f) b[f] = b2[f];
  }
}

// sim[r,c] = thresh(0.5 * V[r].V[c]) -> bf16, row length R. 512 thr, wave tile 32x64.
__global__ __launch_bounds__(512, 4) void k_gram_sim(const bf16_t* __restrict__ V, int R, int K,
                                                     float th, bf16_t* __restrict__ out) {
  int tid = threadIdx.x, lane = tid & 63, w = tid >> 6;
  int wr = w >> 1, wc = w & 1, rq = lane & 15, kq = lane >> 4;
  int r0 = blockIdx.y * 128 + wr * 32, c0 = blockIdx.x * 128 + wc * 64;
  f32x4 acc[2][4];
#pragma unroll
  for (int i = 0; i < 2; ++i)
#pragma unroll
    for (int j = 0; j < 4; ++j) acc[i][j] = 0.f;
  if (K == 256) gramMN<256, 2, 4>(V, r0, c0, rq, kq, acc);
  else          gramMN<128, 2, 4>(V, r0, c0, rq, kq, acc);
#pragma unroll
  for (int fi = 0; fi < 2; ++fi)
#pragma unroll
    for (int fj = 0; fj < 4; ++fj)
#pragma unroll
      for (int reg = 0; reg < 4; ++reg) {
        float s = 0.5f * acc[fi][fj][reg];
        int row = r0 + fi * 16 + kq * 4 + reg;
        int col = c0 + fj * 16 + rq;
        out[(size_t)row * R + col] = (bf16_t)((s < th) ? 0.f : s);
      }
}

// triangle decode with XCD swizzle (528 blocks; 528 % 8 == 0)
static __device__ __forceinline__ void tri_decode(int flat, int& bi, int& bj) {
  int swz = (flat & 7) * 66 + (flat >> 3);
  int b = 0, rem = swz;
  while (rem >= NBLK - b) { rem -= NBLK - b; ++b; }
  bi = b; bj = b + rem;
}

// ---- colsum core: thresholded 32x32 gram; per-lane col partials + row partials ----
template <int K>
static __device__ __forceinline__ void colsum_core(const bf16_t* __restrict__ V, float th,
                                                   int r0, int c0, int rq, int kq,
                                                   float part[2], float rp[8]) {
  f32x4 acc[2][2];
#pragma unroll
  for (int i = 0; i < 2; ++i)
#pragma unroll
    for (int j = 0; j < 2; ++j) acc[i][j] = 0.f;
  gramMN<K, 2, 2>(V, r0, c0, rq, kq, acc);
  part[0] = part[1] = 0.f;
#pragma unroll
  for (int i = 0; i < 8; ++i) rp[i] = 0.f;
#pragma unroll
  for (int fi = 0; fi < 2; ++fi)
#pragma unroll
    for (int fj = 0; fj < 2; ++fj)
#pragma unroll
      for (int reg = 0; reg < 4; ++reg) {
        float s = 0.5f * acc[fi][fj][reg];
        if (s >= th) { part[fj] += s; rp[fi * 4 + reg] += s; }
      }
}

// one channel per blockIdx.y; triangle tiles; NO atomics: plain writes to csPart
// csPart[x][ch][c]: contribution to column c from row-panel x (exactly-once coverage)
__global__ __launch_bounds__(1024, 4) void k_colsum7(
    const bf16_t* __restrict__ Vg, const bf16_t* __restrict__ Vpap, const bf16_t* __restrict__ Vpsp,
    const bf16_t* __restrict__ Vf0, const bf16_t* __restrict__ Vf1,
    const bf16_t* __restrict__ Vs0, const bf16_t* __restrict__ Vs1,
    float* __restrict__ csPart) {
  __shared__ float csred[16][32], rsred[16][32];
  int tid = threadIdx.x, lane = tid & 63, w = tid >> 6;
  int wr = w >> 2, wc = w & 3, rq = lane & 15, kq = lane >> 4;
  int bi, bj; tri_decode(blockIdx.x, bi, bj);
  int ch = blockIdx.y;
  int r0 = bi * 128 + wr * 32, c0 = bj * 128 + wc * 32;
  float part[2], rp[8];
  switch (ch) {
    case 0: colsum_core<256>(Vg,   0.1f, r0, c0, rq, kq, part, rp); break;
    case 1: colsum_core<128>(Vpap, 0.1f, r0, c0, rq, kq, part, rp); break;
    case 2: colsum_core<128>(Vpsp, 0.1f, r0, c0, rq, kq, part, rp); break;
    case 3: colsum_core<256>(Vf0,  0.2f, r0, c0, rq, kq, part, rp); break;
    case 4: colsum_core<256>(Vf1,  0.2f, r0, c0, rq, kq, part, rp); break;
    case 5: colsum_core<128>(Vs0,  0.1f, r0, c0, rq, kq, part, rp); break;
    default: colsum_core<128>(Vs1, 0.1f, r0, c0, rq, kq, part, rp); break;
  }
  // column sums over the wave's 32 rows (reduce across kq groups)
#pragma unroll
  for (int fj = 0; fj < 2; ++fj) {
    float p = part[fj];
    p += __shfl_xor(p, 16);
    p += __shfl_xor(p, 32);
    if (kq == 0) csred[w][fj * 16 + rq] = p;
  }
  // row sums over the wave's 32 cols (reduce across rq bits)
#pragma unroll
  for (int i = 0; i < 8; ++i) {
    float r = rp[i];
    r += __shfl_xor(r, 1); r += __shfl_xor(r, 2);
    r += __shfl_xor(r, 4); r += __shfl_xor(r, 8);
    if (rq == 0) rsred[w][(i >> 2) * 16 + kq * 4 + (i & 3)] = r;
  }
  __syncthreads();
  if (tid < 128) {  // direct: row-panel bi contributes to cols of panel bj
    int c = tid, g = c >> 5, l = c & 31;
    float v = csred[g][l] + csred[4 + g][l] + csred[8 + g][l] + csred[12 + g][l];
    csPart[((size_t)bi * 7 + ch) * NT + bj * 128 + c] = v;
  } else if (tid < 256 && bi != bj) {  // mirror: row-panel bj -> cols of panel bi
    int r = tid - 128, g = r >> 5, l = r & 31;
    float v = rsred[g * 4 + 0][l] + rsred[g * 4 + 1][l] + rsred[g * 4 + 2][l] + rsred[g * 4 + 3][l];
    csPart[((size_t)bj * 7 + ch) * NT + bi * 128 + r] = v;
  }
}

// per-column combine coefficients: reduce csPart over row-panels, then formula
__global__ void k_coef(const float* __restrict__ csPart, const float* __restrict__ w8,
                       float* __restrict__ coef) {
  int c = blockIdx.x * 256 + threadIdx.x;
  if (c >= NT) return;
  float css[7];
#pragma unroll
  for (int ch = 0; ch < 7; ++ch) {
    float s = 0.f;
    for (int x = 0; x < 32; ++x) s += csPart[((size_t)x * 7 + ch) * NT + c];
    css[ch] = s;
  }
  float wS0 = w8[0], wS1 = w8[1], wFF0 = w8[2], wFF1 = w8[3];
  float wF0 = w8[4], wF1 = w8[5], wF2 = w8[6], wF3 = w8[7];
  auto mx = [](float x) { return fmaxf(x, 1e-12f); };
  auto ind = [](float x) { return x > 0.f ? 1.f : 0.f; };
  float cssem = wS0 * ind(css[1]) + wS1 * ind(css[2]);
  float csfp = wFF0 * ind(css[3]) + wFF1 * ind(css[4]);
  float cstt = wFF0 * ind(css[5]) + wFF1 * ind(css[6]);
  coef[c]          = wF0 / mx(css[0]);
  coef[NT + c]     = wF1 * wS0 / (mx(css[1]) * mx(cssem));
  coef[2 * NT + c] = wF1 * wS1 / (mx(css[2]) * mx(cssem));
  coef[3 * NT + c] = wF2 * wFF0 / (mx(css[3]) * mx(csfp));
  coef[4 * NT + c] = wF2 * wFF1 / (mx(css[4]) * mx(csfp));
  coef[5 * NT + c] = wF3 * wFF0 / (mx(css[5]) * mx(cstt));
  coef[6 * NT + c] = wF3 * wFF1 / (mx(css[6]) * mx(cstt));
}

template <int K>
static __device__ __forceinline__ void combine_ch(const bf16_t* __restrict__ V,
                                                  const float* __restrict__ cf, float th,
                                                  int r0, int c0, int rq, int kq,
                                                  f32x4 comb[2][2]) {
  f32x4 acc[2][2];
#pragma unroll
  for (int i = 0; i < 2; ++i)
#pragma unroll
    for (int j = 0; j < 2; ++j) acc[i][j] = 0.f;
  gramMN<K, 2, 2>(V, r0, c0, rq, kq, acc);
  float cc0 = cf[c0 + rq], cc1 = cf[c0 + 16 + rq];
#pragma unroll
  for (int fi = 0; fi < 2; ++fi) {
    f32x4 cr = *(const f32x4*)&cf[r0 + fi * 16 + kq * 4];
#pragma unroll
    for (int fj = 0; fj < 2; ++fj) {
      float cc_ = fj ? cc1 : cc0;
#pragma unroll
      for (int reg = 0; reg < 4; ++reg) {
        float s = 0.5f * acc[fi][fj][reg];
        if (s >= th) comb[fi][fj][reg] = fmaf(cr[reg] + cc_, s, comb[fi][fj][reg]);
      }
    }
  }
}

// sym[r,c] = sum_ch (coef[r]+coef[c]) * M_ch[r,c]; triangle; mirror via per-wave LDS
// transpose; fcsPart plain writes (no atomics), exactly-once coverage as in colsum.
__global__ __launch_bounds__(1024, 4) void k_combine(
    const bf16_t* __restrict__ Vg, const bf16_t* __restrict__ Vpap, const bf16_t* __restrict__ Vpsp,
    const bf16_t* __restrict__ Vf0, const bf16_t* __restrict__ Vf1,
    const bf16_t* __restrict__ Vs0, const bf16_t* __restrict__ Vs1,
    const float* __restrict__ coef, float* __restrict__ outAdj, float* __restrict__ fcsPart) {
  __shared__ float ldsT[16][32 * 32];  // 64 KiB per-wave transpose scratch
  __shared__ float csred[16][32], rsred[16][32];
  int tid = threadIdx.x, lane = tid & 63, w = tid >> 6;
  int wr = w >> 2, wc = w & 3, rq = lane & 15, kq = lane >> 4;
  int bi, bj; tri_decode(blockIdx.x, bi, bj);
  int r0 = bi * 128 + wr * 32, c0 = bj * 128 + wc * 32;
  f32x4 comb[2][2];
#pragma unroll
  for (int i = 0; i < 2; ++i)
#pragma unroll
    for (int j = 0; j < 2; ++j) comb[i][j] = 0.f;
  combine_ch<256>(Vg,   coef + 0 * NT, 0.1f, r0, c0, rq, kq, comb);
  combine_ch<128>(Vpap, coef + 1 * NT, 0.1f, r0, c0, rq, kq, comb);
  combine_ch<128>(Vpsp, coef + 2 * NT, 0.1f, r0, c0, rq, kq, comb);
  combine_ch<256>(Vf0,  coef + 3 * NT, 0.2f, r0, c0, rq, kq, comb);
  combine_ch<256>(Vf1,  coef + 4 * NT, 0.2f, r0, c0, rq, kq, comb);
  combine_ch<128>(Vs0,  coef + 5 * NT, 0.1f, r0, c0, rq, kq, comb);
  combine_ch<128>(Vs1,  coef + 6 * NT, 0.1f, r0, c0, rq, kq, comb);

  // direct write + per-wave column partials
  float part[2] = {0.f, 0.f};
#pragma unroll
  for (int fi = 0; fi < 2; ++fi)
#pragma unroll
    for (int fj = 0; fj < 2; ++fj)
#pragma unroll
      for (int reg = 0; reg < 4; ++reg) {
        float v = comb[fi][fj][reg];
        int row = r0 + fi * 16 + kq * 4 + reg;
        int col = c0 + fj * 16 + rq;
        outAdj[(size_t)row * NT + col] = v;
        part[fj] += v;
      }
#pragma unroll
  for (int fj = 0; fj < 2; ++fj) {
    float p = part[fj];
    p += __shfl_xor(p, 16);
    p += __shfl_xor(p, 32);
    if (kq == 0) csred[w][fj * 16 + rq] = p;
  }

  bool mir = (bi != bj);
  if (mir) {
    // mirror write via per-wave LDS transpose (XOR-swizzled); row sums on the fly
    float* T = ldsT[w];
#pragma unroll
    for (int fi = 0; fi < 2; ++fi)
#pragma unroll
      for (int fj = 0; fj < 2; ++fj)
#pragma unroll
        for (int reg = 0; reg < 4; ++reg) {
          int r = fi * 16 + kq * 4 + reg;
          int c = fj * 16 + rq;
          T[c * 32 + (r ^ ((c & 15) << 1))] = comb[fi][fj][reg];
        }
    int hl = lane >> 5, l32 = lane & 31;
    float rsum = 0.f;
#pragma unroll
    for (int cc = 0; cc < 16; ++cc) {
      int c = cc * 2 + hl;
      float v = T[c * 32 + (l32 ^ ((c & 15) << 1))];
      rsum += v;
      outAdj[(size_t)(c0 + c) * NT + r0 + l32] = v;
    }
    rsum += __shfl_xor(rsum, 32);
    if (lane < 32) rsred[w][l32] = rsum;
  }
  __syncthreads();
  if (tid < 128) {
    int c = tid, g = c >> 5, l = c & 31;
    float v = csred[g][l] + csred[4 + g][l] + csred[8 + g][l] + csred[12 + g][l];
    fcsPart[(size_t)bi * NT + bj * 128 + c] = v;
  } else if (tid < 256 && mir) {
    int r = tid - 128, g = r >> 5, l = r & 31;
    float v = rsred[g * 4 + 0][l] + rsred[g * 4 + 1][l] + rsred[g * 4 + 2][l] + rsred[g * 4 + 3][l];
    fcsPart[(size_t)bj * NT + bi * 128 + r] = v;
  }
}

__global__ void k_fcs(const float* __restrict__ fcsPart, float* __restrict__ fcs) {
  int c = blockIdx.x * 256 + threadIdx.x;
  float s = 0.f;
  for (int x = 0; x < 32; ++x) s += fcsPart[(size_t)x * NT + c];
  fcs[c] = s;
}

__global__ void k_scale(float* __restrict__ adj, const float* __restrict__ finalcs) {
  size_t idx = (size_t)blockIdx.x * 256 + threadIdx.x;
  int c = (int)(idx & (NT - 1));
  adj[idx] = adj[idx] / fmaxf(finalcs[c], 1e-12f);
}

// Cpart[kb][M][64] = Arows(bf16 [M][K-chunk]) . Brows(bf16 [64][K-chunk]) (plain store)
__global__ __launch_bounds__(256, 2) void k_gemmT(const bf16_t* __restrict__ A,
                                                  const bf16_t* __restrict__ Bt,
                                                  float* __restrict__ Cpart, int K, int kchunk,
                                                  int m64) {
  int tid = threadIdx.x, lane = tid & 63, w = tid >> 6;
  int rq = lane & 15, kq = lane >> 4;
  int r0 = blockIdx.x * 128 + w * 32;
  int kb = blockIdx.y * kchunk;
  float* Cs = Cpart + (size_t)blockIdx.y * m64;
  f32x4 acc[2][4];
#pragma unroll
  for (int i = 0; i < 2; ++i)
#pragma unroll
    for (int j = 0; j < 4; ++j) acc[i][j] = 0.f;
  const bf16_t* Ap = A + (size_t)(r0 + rq) * K + kb + kq * 8;
  const bf16_t* Bp = Bt + (size_t)rq * K + kb + kq * 8;
#pragma unroll 2
  for (int kc = 0; kc < kchunk; kc += 32) {
    bf16x8 a[2], b[4];
#pragma unroll
    for (int f = 0; f < 2; ++f) a[f] = *(const bf16x8*)(Ap + (size_t)(f * 16) * K + kc);
#pragma unroll
    for (int f = 0; f < 4; ++f) b[f] = *(const bf16x8*)(Bp + (size_t)(f * 16) * K + kc);
#pragma unroll
    for (int fi = 0; fi < 2; ++fi)
#pragma unroll
      for (int fj = 0; fj < 4; ++fj)
        acc[fi][fj] = mfma_bf16(a[fi], b[fj], acc[fi][fj]);
  }
#pragma unroll
  for (int fi = 0; fi < 2; ++fi)
#pragma unroll
    for (int fj = 0; fj < 4; ++fj)
#pragma unroll
      for (int reg = 0; reg < 4; ++reg) {
        int row = r0 + fi * 16 + kq * 4 + reg;
        int col = fj * 16 + rq;
        Cs[(size_t)row * 64 + col] = acc[fi][fj][reg];
      }
}

// out[i] = sum_{s<8} part[s*n + i]
__global__ void k_red8(const float* __restrict__ part, int n, float* __restrict__ out) {
  int i = blockIdx.x * 256 + threadIdx.x;
  if (i >= n) return;
  float s = 0.f;
#pragma unroll
  for (int q = 0; q < 8; ++q) s += part[(size_t)q * n + i];
  out[i] = s;
}

// ---------------- f32 tile GEMMs (precision-sensitive tail) ----------------

__global__ __launch_bounds__(256) void k_gemm_n64(const float* __restrict__ A, int K,
                                                  const float* __restrict__ B,
                                                  float* __restrict__ C,
                                                  const float* __restrict__ bias, int relu) {
  __shared__ float As[64][68], Bs[64][68];
  int r0 = blockIdx.x * 64;
  int tid = threadIdx.x, tx = tid & 15, ty = tid >> 4;
  float acc[4][4] = {};
  for (int kc = 0; kc < K; kc += 64) {
    __syncthreads();
#pragma unroll
    for (int m = 0; m < 16; ++m) {
      int lin = tid + 256 * m;
      int row = lin >> 6, col = lin & 63;
      As[col][row] = A[(size_t)(r0 + row) * K + kc + col];
      Bs[row][col] = B[(size_t)(kc + row) * 64 + col];
    }
    __syncthreads();
#pragma unroll 8
    for (int k = 0; k < 64; ++k) {
      float a[4], b[4];
#pragma unroll
      for (int i = 0; i < 4; ++i) a[i] = As[k][ty * 4 + i];
#pragma unroll
      for (int j = 0; j < 4; ++j) b[j] = Bs[k][tx * 4 + j];
#pragma unroll
      for (int i = 0; i < 4; ++i)
#pragma unroll
        for (int j = 0; j < 4; ++j)
          acc[i][j] = fmaf(a[i], b[j], acc[i][j]);
    }
  }
#pragma unroll
  for (int i = 0; i < 4; ++i)
#pragma unroll
    for (int j = 0; j < 4; ++j) {
      float v = acc[i][j];
      if (bias) v += bias[tx * 4 + j];
      if (relu) v = fmaxf(v, 0.f);
      C[(size_t)(r0 + ty * 4 + i) * 64 + tx * 4 + j] = v;
    }
}

// split-K f32: Cpart[kb][M][64] = A[M][K-chunk] @ B[K][64]  (plain store)
__global__ __launch_bounds__(256) void k_gemm_n64_sk(const float* __restrict__ A, int K,
                                                     int kchunk, const float* __restrict__ B,
                                                     float* __restrict__ Cpart) {
  __shared__ float As[64][68], Bs[64][68];
  int r0 = blockIdx.x * 64;
  int kb = blockIdx.y * kchunk;
  float* Cs = Cpart + (size_t)blockIdx.y * (NT * 64);
  int tid = threadIdx.x, tx = tid & 15, ty = tid >> 4;
  float acc[4][4] = {};
  for (int kc = kb; kc < kb + kchunk; kc += 64) {
    __syncthreads();
#pragma unroll
    for (int m = 0; m < 16; ++m) {
      int lin = tid + 256 * m;
      int row = lin >> 6, col = lin & 63;
      As[col][row] = A[(size_t)(r0 + row) * K + kc + col];
      Bs[row][col] = B[(size_t)(kc + row) * 64 + col];
    }
    __syncthreads();
#pragma unroll 8
    for (int k = 0; k < 64; ++k) {
      float a[4], b[4];
#pragma unroll
      for (int i = 0; i < 4; ++i) a[i] = As[k][ty * 4 + i];
#pragma unroll
      for (int j = 0; j < 4; ++j) b[j] = Bs[k][tx * 4 + j];
#pragma unroll
      for (int i = 0; i < 4; ++i)
#pragma unroll
        for (int j = 0; j < 4; ++j)
          acc[i][j] = fmaf(a[i], b[j], acc[i][j]);
    }
  }
#pragma unroll
  for (int i = 0; i < 4; ++i)
#pragma unroll
    for (int j = 0; j < 4; ++j)
      Cs[(size_t)(r0 + ty * 4 + i) * 64 + tx * 4 + j] = acc[i][j];
}

// X1[i] = relu(sum_{s<8} part[s][i] + b[i&63])
__global__ void k_redbias_relu(const float* __restrict__ part, const float* __restrict__ b,
                               float* __restrict__ X) {
  int i = blockIdx.x * 256 + threadIdx.x;
  float s = 0.f;
#pragma unroll
  for (int q = 0; q < 8; ++q) s += part[(size_t)q * (NT * 64) + i];
  X[i] = fmaxf(s + b[i & 63], 0.f);
}

// P2[r,0:3] = X1[r,:] @ W2
__global__ void k_p2(const float* __restrict__ X1, const float* __restrict__ W2,
                     float* __restrict__ P2) {
  int r = blockIdx.x * 64 + threadIdx.x;
  float a0 = 0.f, a1 = 0.f, a2 = 0.f;
#pragma unroll 8
  for (int k = 0; k < 64; ++k) {
    float x = X1[(size_t)r * 64 + k];
    a0 = fmaf(x, W2[k * 3 + 0], a0);
    a1 = fmaf(x, W2[k * 3 + 1], a1);
    a2 = fmaf(x, W2[k * 3 + 2], a2);
  }
  P2[r * 4 + 0] = a0; P2[r * 4 + 1] = a1; P2[r * 4 + 2] = a2;
}

// logits[r,:] = log_softmax(adj[r,:] @ P2 + b2)
__global__ void k_out(const float* __restrict__ adj, const float* __restrict__ P2,
                      const float* __restrict__ b2, float* __restrict__ logits) {
  int r = blockIdx.x, t = threadIdx.x;  // 64 threads
  const float* arow = adj + (size_t)r * NT;
  float a0 = 0.f, a1 = 0.f, a2 = 0.f;
  for (int c = t; c < NT; c += 64) {
    float a = arow[c];
    a0 = fmaf(a, P2[c * 4 + 0], a0);
    a1 = fmaf(a, P2[c * 4 + 1], a1);
    a2 = fmaf(a, P2[c * 4 + 2], a2);
  }
  for (int off = 32; off; off >>= 1) {
    a0 += __shfl_xor(a0, off);
    a1 += __shfl_xor(a1, off);
    a2 += __shfl_xor(a2, off);
  }
  if (t == 0) {
    a0 += b2[0]; a1 += b2[1]; a2 += b2[2];
    float m = fmaxf(a0, fmaxf(a1, a2));
    float lse = m + logf(expf(a0 - m) + expf(a1 - m) + expf(a2 - m));
    logits[r * 3 + 0] = a0 - lse;
    logits[r * 3 + 1] = a1 - lse;
    logits[r * 3 + 2] = a2 - lse;
  }
}

// ---------------- host ----------------

extern "C" void kernel_launch(void* const* d_in, const int* in_sizes, int n_in,
                              void* d_out, int out_size, void* d_ws, size_t ws_size,
                              hipStream_t stream) {
  (void)in_sizes; (void)n_in; (void)out_size; (void)ws_size;
  const float* features = (const float*)d_in[0];
  const float* adj      = (const float*)d_in[1];
  const float* mp_pap   = (const float*)d_in[2];
  const float* mp_psp   = (const float*)d_in[3];
  const float* fgo_w    = (const float*)d_in[6];
  const float* fpo_w    = (const float*)d_in[7];
  const float* sgg_pap_w = (const float*)d_in[8];
  const float* sgg_psp_w = (const float*)d_in[9];
  const float* sg_agg_w  = (const float*)d_in[10];
  const float* f_agg_f_w = (const float*)d_in[11];
  const float* f_agg_w   = (const float*)d_in[12];
  const float* topo_W_a  = (const float*)d_in[13];
  const float* topo_b_a  = (const float*)d_in[14];
  const float* topo_W_s  = (const float*)d_in[15];
  const float* topo_b_s  = (const float*)d_in[16];
  const float* fgt_w_a   = (const float*)d_in[17];
  const float* fgt_w_s   = (const float*)d_in[18];
  const float* gcn_W1    = (const float*)d_in[19];
  const float* gcn_b1    = (const float*)d_in[20];
  const float* gcn_W2    = (const float*)d_in[21];
  const float* gcn_b2    = (const float*)d_in[22];

  float* logits = (float*)d_out;
  float* adjOut = (float*)d_out + (size_t)NT * 3;      // 4096x4096 f32 output
  bf16_t* simA  = (bf16_t*)adjOut;                     // scratch lifetime before combine

  float* ws = (float*)d_ws;
  size_t o = 0;
  bf16_t* Vg   = (bf16_t*)(ws + o); o += (size_t)NT * 128;   // NT x 256 bf16
  bf16_t* Vfa  = (bf16_t*)(ws + o); o += (size_t)NA * 128;
  bf16_t* Vf0  = (bf16_t*)(ws + o); o += (size_t)NT * 128;
  bf16_t* Vf1  = (bf16_t*)(ws + o); o += (size_t)NT * 128;
  bf16_t* Vpap = (bf16_t*)(ws + o); o += (size_t)NT * 64;    // NT x 128 bf16
  bf16_t* Vpsp = (bf16_t*)(ws + o); o += (size_t)NT * 64;
  bf16_t* Vs0  = (bf16_t*)(ws + o); o += (size_t)NT * 64;
  bf16_t* Vs1  = (bf16_t*)(ws + o); o += (size_t)NT * 64;
  bf16_t* Vfs  = (bf16_t*)(ws + o); o += (size_t)NS * 128;
  bf16_t* simS = (bf16_t*)(ws + o); o += (size_t)NS * NS / 2;
  bf16_t* WaT  = (bf16_t*)(ws + o); o += (size_t)64 * NA / 2;
  bf16_t* WsT  = (bf16_t*)(ws + o); o += (size_t)64 * NS / 2;
  float* fpa  = ws + o; o += (size_t)NT * 128;
  float* fps  = ws + o; o += (size_t)NT * 128;
  float* Sa   = ws + o; o += (size_t)NA * 64;
  float* Ss   = ws + o; o += (size_t)NS * 64;
  float* SaPart = ws + o; o += (size_t)8 * NA * 64;
  float* SsPart = ws + o; o += (size_t)8 * NS * 64;
  float* topoA = ws + o; o += (size_t)NT * 64;
  float* topoS = ws + o; o += (size_t)NT * 64;
  float* H1   = ws + o; o += (size_t)NT * 64;
  float* X1   = ws + o; o += (size_t)NT * 64;
  float* X1Part = ws + o; o += (size_t)8 * NT * 64;
  float* P2   = ws + o; o += (size_t)NT * 4;
  float* csPart = ws + o; o += (size_t)32 * 7 * NT;
  float* fcsPart = ws + o; o += (size_t)32 * NT;
  float* fcs  = ws + o; o += NT;
  float* coef = ws + o; o += (size_t)7 * NT;
  float* w8   = ws + o; o += 8;

  k_weights<<<1, 1, 0, stream>>>(sg_agg_w, f_agg_f_w, f_agg_w, w8);

  // normalized head-weighted feature vectors (bf16)
  k_rownorm<<<NT, 64, 0, stream>>>(features, 128, fgo_w, Vg);
  k_rownorm<<<NT, 64, 0, stream>>>(mp_pap, 64, sgg_pap_w, Vpap);
  k_rownorm<<<NT, 64, 0, stream>>>(mp_psp, 64, sgg_psp_w, Vpsp);
  k_rownorm<<<NA, 64, 0, stream>>>(features + (size_t)NT * 128, 128, fgo_w, Vfa);
  k_rownorm<<<NS, 64, 0, stream>>>(features + (size_t)(NT + NA) * 128, 128, fgo_w, Vfs);

  // feat_prop = ori_g @ fmat_r  (sparse ballot-scan)
  k_spmm128<<<NT, 128, 0, stream>>>(adj, NT, NA, features + (size_t)NT * 128, fpa);
  k_spmm128<<<NT, 128, 0, stream>>>(adj, NT + NA, NS, features + (size_t)(NT + NA) * 128, fps);
  k_rownorm<<<NT, 64, 0, stream>>>(fpa, 128, fpo_w, Vf0);
  k_rownorm<<<NT, 64, 0, stream>>>(fps, 128, fpo_w, Vf1);

  // topo weight transposes (bf16 rows)
  k_transp<<<(NA * 64) / 256, 256, 0, stream>>>(topo_W_a, NA, WaT);
  k_transp<<<(NS * 64) / 256, 256, 0, stream>>>(topo_W_s, NS, WsT);

  // sim_r (thresholded, bf16) and S_r = sim_r @ topo_W (MFMA split-K, partials+reduce)
  k_gram_sim<<<dim3(NA / 128, NA / 128), 512, 0, stream>>>(Vfa, NA, 256, 0.1f, simA);
  k_gram_sim<<<dim3(NS / 128, NS / 128), 512, 0, stream>>>(Vfs, NS, 256, 0.1f, simS);
  k_gemmT<<<dim3(NA / 128, 8), 256, 0, stream>>>(simA, WaT, SaPart, NA, NA / 8, NA * 64);
  k_gemmT<<<dim3(NS / 128, 8), 256, 0, stream>>>(simS, WsT, SsPart, NS, NS / 8, NS * 64);
  k_red8<<<(NA * 64) / 256, 256, 0, stream>>>(SaPart, NA * 64, Sa);
  k_red8<<<(NS * 64) / 256, 256, 0, stream>>>(SsPart, NS * 64, Ss);

  // topo_hid = ori_g @ S_r + b
  k_spmm64<<<NT, 128, 0, stream>>>(adj, NT, NA, Sa, topo_b_a, topoA);
  k_spmm64<<<NT, 128, 0, stream>>>(adj, NT + NA, NS, Ss, topo_b_s, topoS);
  k_rownorm<<<NT, 64, 0, stream>>>(topoA, 64, fgt_w_a, Vs0);
  k_rownorm<<<NT, 64, 0, stream>>>(topoS, 64, fgt_w_s, Vs1);

  // pass 1: per-channel column sums, channel-split grid, no atomics -> coefficients
  k_colsum7<<<dim3((NBLK * (NBLK + 1)) / 2, 7), 1024, 0, stream>>>(
      Vg, Vpap, Vpsp, Vf0, Vf1, Vs0, Vs1, csPart);
  k_coef<<<NT / 256, 256, 0, stream>>>(csPart, w8, coef);

  // pass 2: combine + symmetrize, triangle + LDS-transposed mirror, no atomics
  k_combine<<<(NBLK * (NBLK + 1)) / 2, 1024, 0, stream>>>(Vg, Vpap, Vpsp, Vf0, Vf1, Vs0, Vs1,
                                                          coef, adjOut, fcsPart);
  k_fcs<<<NT / 256, 256, 0, stream>>>(fcsPart, fcs);
  k_scale<<<(NT * NT) / 256, 256, 0, stream>>>(adjOut, fcs);

  // GCN (f32 tail, split-K partials + fused reduce)
  k_gemm_n64<<<NT / 64, 256, 0, stream>>>(features, 128, gcn_W1, H1, nullptr, 0);
  k_gemm_n64_sk<<<dim3(NT / 64, 8), 256, 0, stream>>>(adjOut, NT, NT / 8, H1, X1Part);
  k_redbias_relu<<<(NT * 64) / 256, 256, 0, stream>>>(X1Part, gcn_b1, X1);
  k_p2<<<NT / 64, 64, 0, stream>>>(X1, gcn_W2, P2);
  k_out<<<NT, 64, 0, stream>>>(adjOut, P2, gcn_b2, logits);
}

// Round 7
// 899.740 us; speedup vs baseline: 1.4816x; 1.3170x over previous
//
#include <hip/hip_runtime.h>
#include <math.h>

#define NT 4096
#define NA 4096
#define NS 1024
#define NALL 9216
#define NBLK 32   // NT/128
#define KC 64     // staging K-chunk

typedef __bf16 bf16_t;
typedef bf16_t bf16x8 __attribute__((ext_vector_type(8)));
typedef float f32x4 __attribute__((ext_vector_type(4)));

static __device__ __forceinline__ f32x4 mfma_bf16(bf16x8 a, bf16x8 b, f32x4 c) {
  return __builtin_amdgcn_mfma_f32_16x16x32_bf16(a, b, c, 0, 0, 0);
}

// ---------------- small prep kernels ----------------

__global__ void k_weights(const float* __restrict__ sg, const float* __restrict__ ff,
                          const float* __restrict__ f4, float* __restrict__ w8) {
  float m = fmaxf(sg[0], sg[1]);
  float e0 = expf(sg[0] - m), e1 = expf(sg[1] - m);
  w8[0] = e0 / (e0 + e1); w8[1] = e1 / (e0 + e1);
  m = fmaxf(ff[0], ff[1]);
  e0 = expf(ff[0] - m); e1 = expf(ff[1] - m);
  w8[2] = e0 / (e0 + e1); w8[3] = e1 / (e0 + e1);
  m = fmaxf(fmaxf(f4[0], f4[1]), fmaxf(f4[2], f4[3]));
  float a0 = expf(f4[0] - m), a1 = expf(f4[1] - m), a2 = expf(f4[2] - m), a3 = expf(f4[3] - m);
  float s = a0 + a1 + a2 + a3;
  w8[4] = a0 / s; w8[5] = a1 / s; w8[6] = a2 / s; w8[7] = a3 / s;
}

// V[r, h*D+d] = (src[r,d]*w[h,d]) / max(||src[r,:]*w[h,:]||, 1e-12), output bf16
__global__ void k_rownorm(const float* __restrict__ src, int D,
                          const float* __restrict__ w, bf16_t* __restrict__ V) {
  int r = blockIdx.x;
  int t = threadIdx.x;  // 64 threads = 1 wave
  const float* x = src + (size_t)r * D;
  bf16_t* out = V + (size_t)r * (2 * D);
  for (int h = 0; h < 2; ++h) {
    float ss = 0.f;
    for (int d = t; d < D; d += 64) {
      float y = x[d] * w[h * D + d];
      ss = fmaf(y, y, ss);
    }
    for (int off = 32; off; off >>= 1) ss += __shfl_xor(ss, off);
    float nrm = fmaxf(sqrtf(ss), 1e-12f);
    for (int d = t; d < D; d += 64) {
      float y = x[d] * w[h * D + d];
      out[h * D + d] = (bf16_t)(y / nrm);
    }
  }
}

// out[r,0:128] = sum_c adj[r, colbase+c] * feats[c, 0:128]   (adj ~0.5% dense; ballot scan)
__global__ void k_spmm128(const float* __restrict__ adj, int colbase, int ncols,
                          const float* __restrict__ feats, float* __restrict__ out) {
  int r = blockIdx.x, t = threadIdx.x, wv = t >> 6, lane = t & 63;  // 128 thr = 2 waves
  const float* arow = adj + (size_t)r * NALL + colbase;
  float acc0 = 0.f, acc1 = 0.f;
  for (int c0 = wv * 64; c0 < ncols; c0 += 128) {
    float a = arow[c0 + lane];
    unsigned long long m = __ballot(a != 0.f);
    while (m) {
      int b = __builtin_ctzll(m); m &= m - 1;
      float v = __shfl(a, b);
      const float* f = feats + (size_t)(c0 + b) * 128;
      acc0 = fmaf(v, f[lane], acc0);
      acc1 = fmaf(v, f[lane + 64], acc1);
    }
  }
  __shared__ float red[2][128];
  red[wv][lane] = acc0; red[wv][lane + 64] = acc1;
  __syncthreads();
  if (t < 128) out[(size_t)r * 128 + t] = red[0][t] + red[1][t];
}

// out[r,0:64] = sum_c adj[r, colbase+c] * S[c,0:64] + bias
__global__ void k_spmm64(const float* __restrict__ adj, int colbase, int ncols,
                         const float* __restrict__ S, const float* __restrict__ bias,
                         float* __restrict__ out) {
  int r = blockIdx.x, t = threadIdx.x, wv = t >> 6, lane = t & 63;  // 128 thr = 2 waves
  const float* arow = adj + (size_t)r * NALL + colbase;
  float acc = 0.f;
  for (int c0 = wv * 64; c0 < ncols; c0 += 128) {
    float a = arow[c0 + lane];
    unsigned long long m = __ballot(a != 0.f);
    while (m) {
      int b = __builtin_ctzll(m); m &= m - 1;
      float v = __shfl(a, b);
      acc = fmaf(v, S[(size_t)(c0 + b) * 64 + lane], acc);
    }
  }
  __shared__ float red[2][64];
  red[wv][lane] = acc;
  __syncthreads();
  if (t < 64) out[(size_t)r * 64 + t] = red[0][t] + red[1][t] + bias[t];
}

// Wt[n][k] = (bf16) W[k][n]   (W: [K][64] f32)
__global__ void k_transp(const float* __restrict__ W, int K, bf16_t* __restrict__ Wt) {
  int idx = blockIdx.x * 256 + threadIdx.x;
  int n = idx & 63, k = idx >> 6;
  if (k < K) Wt[(size_t)n * K + k] = (bf16_t)W[(size_t)k * 64 + n];
}

// -------- LDS-staged Gram core: block tile 128x128, 16 waves of 32x32 ----------
// Stage A/B 128xKC panels coalesced into swizzled LDS, consume via ds_read_b128.
// Swizzle: element offset (col ^ ((row&7)*8)) -> byte ^ ((row&7)<<4); reads 2-way free.

template <int K>
static __device__ __forceinline__ void gram_staged(
    const bf16_t* __restrict__ V, int rowA, int rowB,
    bf16_t* __restrict__ As, bf16_t* __restrict__ Bs,
    int tid, int wr, int wc, int rq, int kq, f32x4 acc[2][2]) {
  int srow = tid >> 3, scol = (tid & 7) * 8;
  int soff = srow * KC + (scol ^ ((srow & 7) * 8));
  const bf16_t* gA = V + (size_t)(rowA + srow) * K + scol;
  const bf16_t* gB = V + (size_t)(rowB + srow) * K + scol;
  int lrA0 = wr * 32 + rq, lrA1 = lrA0 + 16;
  int lrB0 = wc * 32 + rq, lrB1 = lrB0 + 16;
#pragma unroll
  for (int kc = 0; kc < K; kc += KC) {
    __syncthreads();  // protect previous chunk (and previous channel) reads
    *(bf16x8*)(As + soff) = *(const bf16x8*)(gA + kc);
    *(bf16x8*)(Bs + soff) = *(const bf16x8*)(gB + kc);
    __syncthreads();
#pragma unroll
    for (int kk = 0; kk < 2; ++kk) {
      int ccol = kk * 32 + kq * 8;
      bf16x8 a0 = *(const bf16x8*)(As + lrA0 * KC + (ccol ^ ((lrA0 & 7) * 8)));
      bf16x8 a1 = *(const bf16x8*)(As + lrA1 * KC + (ccol ^ ((lrA1 & 7) * 8)));
      bf16x8 b0 = *(const bf16x8*)(Bs + lrB0 * KC + (ccol ^ ((lrB0 & 7) * 8)));
      bf16x8 b1 = *(const bf16x8*)(Bs + lrB1 * KC + (ccol ^ ((lrB1 & 7) * 8)));
      acc[0][0] = mfma_bf16(a0, b0, acc[0][0]);
      acc[0][1] = mfma_bf16(a0, b1, acc[0][1]);
      acc[1][0] = mfma_bf16(a1, b0, acc[1][0]);
      acc[1][1] = mfma_bf16(a1, b1, acc[1][1]);
    }
  }
}

// sim[r,c] = thresh(0.5 * V[r].V[c]) -> bf16, row length R. 1024 thr, tile 128x128.
__global__ __launch_bounds__(1024, 4) void k_gram_sim(const bf16_t* __restrict__ V, int R, int K,
                                                      float th, bf16_t* __restrict__ out) {
  __shared__ __align__(16) bf16_t As[128 * KC], Bs[128 * KC];
  int tid = threadIdx.x, lane = tid & 63, w = tid >> 6;
  int wr = w >> 2, wc = w & 3, rq = lane & 15, kq = lane >> 4;
  int rowA = blockIdx.y * 128, rowB = blockIdx.x * 128;
  f32x4 acc[2][2];
#pragma unroll
  for (int i = 0; i < 2; ++i)
#pragma unroll
    for (int j = 0; j < 2; ++j) acc[i][j] = 0.f;
  if (K == 256) gram_staged<256>(V, rowA, rowB, As, Bs, tid, wr, wc, rq, kq, acc);
  else          gram_staged<128>(V, rowA, rowB, As, Bs, tid, wr, wc, rq, kq, acc);
  int r0 = rowA + wr * 32, c0 = rowB + wc * 32;
#pragma unroll
  for (int fi = 0; fi < 2; ++fi)
#pragma unroll
    for (int fj = 0; fj < 2; ++fj)
#pragma unroll
      for (int reg = 0; reg < 4; ++reg) {
        float s = 0.5f * acc[fi][fj][reg];
        int row = r0 + fi * 16 + kq * 4 + reg;
        int col = c0 + fj * 16 + rq;
        out[(size_t)row * R + col] = (bf16_t)((s < th) ? 0.f : s);
      }
}

// triangle decode with XCD swizzle (528 blocks; 528 % 8 == 0)
static __device__ __forceinline__ void tri_decode(int flat, int& bi, int& bj) {
  int swz = (flat & 7) * 66 + (flat >> 3);
  int b = 0, rem = swz;
  while (rem >= NBLK - b) { rem -= NBLK - b; ++b; }
  bi = b; bj = b + rem;
}

// ---- colsum: staged gram + thresholded partials ----
template <int K>
static __device__ __forceinline__ void colsum_core(const bf16_t* __restrict__ V, float th,
                                                   bf16_t* As, bf16_t* Bs,
                                                   int tid, int wr, int wc, int rq, int kq,
                                                   int rowA, int rowB,
                                                   float part[2], float rp[8]) {
  f32x4 acc[2][2];
#pragma unroll
  for (int i = 0; i < 2; ++i)
#pragma unroll
    for (int j = 0; j < 2; ++j) acc[i][j] = 0.f;
  gram_staged<K>(V, rowA, rowB, As, Bs, tid, wr, wc, rq, kq, acc);
  part[0] = part[1] = 0.f;
#pragma unroll
  for (int i = 0; i < 8; ++i) rp[i] = 0.f;
#pragma unroll
  for (int fi = 0; fi < 2; ++fi)
#pragma unroll
    for (int fj = 0; fj < 2; ++fj)
#pragma unroll
      for (int reg = 0; reg < 4; ++reg) {
        float s = 0.5f * acc[fi][fj][reg];
        if (s >= th) { part[fj] += s; rp[fi * 4 + reg] += s; }
      }
}

// one channel per blockIdx.y; triangle tiles; NO atomics: plain writes to csPart
__global__ __launch_bounds__(1024, 4) void k_colsum7(
    const bf16_t* __restrict__ Vg, const bf16_t* __restrict__ Vpap, const bf16_t* __restrict__ Vpsp,
    const bf16_t* __restrict__ Vf0, const bf16_t* __restrict__ Vf1,
    const bf16_t* __restrict__ Vs0, const bf16_t* __restrict__ Vs1,
    float* __restrict__ csPart) {
  __shared__ __align__(16) bf16_t As[128 * KC], Bs[128 * KC];
  __shared__ float csred[16][32], rsred[16][32];
  int tid = threadIdx.x, lane = tid & 63, w = tid >> 6;
  int wr = w >> 2, wc = w & 3, rq = lane & 15, kq = lane >> 4;
  int bi, bj; tri_decode(blockIdx.x, bi, bj);
  int ch = blockIdx.y;
  int rowA = bi * 128, rowB = bj * 128;
  float part[2], rp[8];
  switch (ch) {
    case 0: colsum_core<256>(Vg,   0.1f, As, Bs, tid, wr, wc, rq, kq, rowA, rowB, part, rp); break;
    case 1: colsum_core<128>(Vpap, 0.1f, As, Bs, tid, wr, wc, rq, kq, rowA, rowB, part, rp); break;
    case 2: colsum_core<128>(Vpsp, 0.1f, As, Bs, tid, wr, wc, rq, kq, rowA, rowB, part, rp); break;
    case 3: colsum_core<256>(Vf0,  0.2f, As, Bs, tid, wr, wc, rq, kq, rowA, rowB, part, rp); break;
    case 4: colsum_core<256>(Vf1,  0.2f, As, Bs, tid, wr, wc, rq, kq, rowA, rowB, part, rp); break;
    case 5: colsum_core<128>(Vs0,  0.1f, As, Bs, tid, wr, wc, rq, kq, rowA, rowB, part, rp); break;
    default: colsum_core<128>(Vs1, 0.1f, As, Bs, tid, wr, wc, rq, kq, rowA, rowB, part, rp); break;
  }
  // column sums over the wave's 32 rows (reduce across kq groups)
#pragma unroll
  for (int fj = 0; fj < 2; ++fj) {
    float p = part[fj];
    p += __shfl_xor(p, 16);
    p += __shfl_xor(p, 32);
    if (kq == 0) csred[w][fj * 16 + rq] = p;
  }
  // row sums over the wave's 32 cols (reduce across rq bits)
#pragma unroll
  for (int i = 0; i < 8; ++i) {
    float r = rp[i];
    r += __shfl_xor(r, 1); r += __shfl_xor(r, 2);
    r += __shfl_xor(r, 4); r += __shfl_xor(r, 8);
    if (rq == 0) rsred[w][(i >> 2) * 16 + kq * 4 + (i & 3)] = r;
  }
  __syncthreads();
  if (tid < 128) {  // direct: row-panel bi -> cols of panel bj
    int c = tid, g = c >> 5, l = c & 31;
    float v = csred[g][l] + csred[4 + g][l] + csred[8 + g][l] + csred[12 + g][l];
    csPart[((size_t)bi * 7 + ch) * NT + bj * 128 + c] = v;
  } else if (tid < 256 && bi != bj) {  // mirror: row-panel bj -> cols of panel bi
    int r = tid - 128, g = r >> 5, l = r & 31;
    float v = rsred[g * 4 + 0][l] + rsred[g * 4 + 1][l] + rsred[g * 4 + 2][l] + rsred[g * 4 + 3][l];
    csPart[((size_t)bj * 7 + ch) * NT + bi * 128 + r] = v;
  }
}

// per-column combine coefficients: reduce csPart over row-panels, then formula
__global__ void k_coef(const float* __restrict__ csPart, const float* __restrict__ w8,
                       float* __restrict__ coef) {
  int c = blockIdx.x * 256 + threadIdx.x;
  if (c >= NT) return;
  float css[7];
#pragma unroll
  for (int ch = 0; ch < 7; ++ch) {
    float s = 0.f;
    for (int x = 0; x < 32; ++x) s += csPart[((size_t)x * 7 + ch) * NT + c];
    css[ch] = s;
  }
  float wS0 = w8[0], wS1 = w8[1], wFF0 = w8[2], wFF1 = w8[3];
  float wF0 = w8[4], wF1 = w8[5], wF2 = w8[6], wF3 = w8[7];
  auto mx = [](float x) { return fmaxf(x, 1e-12f); };
  auto ind = [](float x) { return x > 0.f ? 1.f : 0.f; };
  float cssem = wS0 * ind(css[1]) + wS1 * ind(css[2]);
  float csfp = wFF0 * ind(css[3]) + wFF1 * ind(css[4]);
  float cstt = wFF0 * ind(css[5]) + wFF1 * ind(css[6]);
  coef[c]          = wF0 / mx(css[0]);
  coef[NT + c]     = wF1 * wS0 / (mx(css[1]) * mx(cssem));
  coef[2 * NT + c] = wF1 * wS1 / (mx(css[2]) * mx(cssem));
  coef[3 * NT + c] = wF2 * wFF0 / (mx(css[3]) * mx(csfp));
  coef[4 * NT + c] = wF2 * wFF1 / (mx(css[4]) * mx(csfp));
  coef[5 * NT + c] = wF3 * wFF0 / (mx(css[5]) * mx(cstt));
  coef[6 * NT + c] = wF3 * wFF1 / (mx(css[6]) * mx(cstt));
}

template <int K>
static __device__ __forceinline__ void combine_ch(const bf16_t* __restrict__ V,
                                                  const float* __restrict__ cf, float th,
                                                  bf16_t* As, bf16_t* Bs,
                                                  int tid, int wr, int wc, int rq, int kq,
                                                  int rowA, int rowB, int r0, int c0,
                                                  f32x4 comb[2][2]) {
  f32x4 acc[2][2];
#pragma unroll
  for (int i = 0; i < 2; ++i)
#pragma unroll
    for (int j = 0; j < 2; ++j) acc[i][j] = 0.f;
  gram_staged<K>(V, rowA, rowB, As, Bs, tid, wr, wc, rq, kq, acc);
  float cc0 = cf[c0 + rq], cc1 = cf[c0 + 16 + rq];
#pragma unroll
  for (int fi = 0; fi < 2; ++fi) {
    f32x4 cr = *(const f32x4*)&cf[r0 + fi * 16 + kq * 4];
#pragma unroll
    for (int fj = 0; fj < 2; ++fj) {
      float cc_ = fj ? cc1 : cc0;
#pragma unroll
      for (int reg = 0; reg < 4; ++reg) {
        float s = 0.5f * acc[fi][fj][reg];
        if (s >= th) comb[fi][fj][reg] = fmaf(cr[reg] + cc_, s, comb[fi][fj][reg]);
      }
    }
  }
}

// sym[r,c] = sum_ch (coef[r]+coef[c]) * M_ch[r,c]; triangle; mirror via per-wave LDS
// transpose (union with staging buffers); fcsPart plain writes, exactly-once coverage.
__global__ __launch_bounds__(1024, 4) void k_combine(
    const bf16_t* __restrict__ Vg, const bf16_t* __restrict__ Vpap, const bf16_t* __restrict__ Vpsp,
    const bf16_t* __restrict__ Vf0, const bf16_t* __restrict__ Vf1,
    const bf16_t* __restrict__ Vs0, const bf16_t* __restrict__ Vs1,
    const float* __restrict__ coef, float* __restrict__ outAdj, float* __restrict__ fcsPart) {
  __shared__ __align__(16) unsigned char smem[65536];  // union: As+Bs (32K) | ldsT (64K)
  __shared__ float csred[16][32], rsred[16][32];
  bf16_t* As = (bf16_t*)smem;
  bf16_t* Bs = (bf16_t*)(smem + 16384);
  float* ldsT = (float*)smem;  // 16 waves x 1024 floats
  int tid = threadIdx.x, lane = tid & 63, w = tid >> 6;
  int wr = w >> 2, wc = w & 3, rq = lane & 15, kq = lane >> 4;
  int bi, bj; tri_decode(blockIdx.x, bi, bj);
  int rowA = bi * 128, rowB = bj * 128;
  int r0 = rowA + wr * 32, c0 = rowB + wc * 32;
  f32x4 comb[2][2];
#pragma unroll
  for (int i = 0; i < 2; ++i)
#pragma unroll
    for (int j = 0; j < 2; ++j) comb[i][j] = 0.f;
  combine_ch<256>(Vg,   coef + 0 * NT, 0.1f, As, Bs, tid, wr, wc, rq, kq, rowA, rowB, r0, c0, comb);
  combine_ch<128>(Vpap, coef + 1 * NT, 0.1f, As, Bs, tid, wr, wc, rq, kq, rowA, rowB, r0, c0, comb);
  combine_ch<128>(Vpsp, coef + 2 * NT, 0.1f, As, Bs, tid, wr, wc, rq, kq, rowA, rowB, r0, c0, comb);
  combine_ch<256>(Vf0,  coef + 3 * NT, 0.2f, As, Bs, tid, wr, wc, rq, kq, rowA, rowB, r0, c0, comb);
  combine_ch<256>(Vf1,  coef + 4 * NT, 0.2f, As, Bs, tid, wr, wc, rq, kq, rowA, rowB, r0, c0, comb);
  combine_ch<128>(Vs0,  coef + 5 * NT, 0.1f, As, Bs, tid, wr, wc, rq, kq, rowA, rowB, r0, c0, comb);
  combine_ch<128>(Vs1,  coef + 6 * NT, 0.1f, As, Bs, tid, wr, wc, rq, kq, rowA, rowB, r0, c0, comb);
  __syncthreads();  // staging buffers -> transpose scratch phase boundary

  // direct write + per-wave column partials
  float part[2] = {0.f, 0.f};
#pragma unroll
  for (int fi = 0; fi < 2; ++fi)
#pragma unroll
    for (int fj = 0; fj < 2; ++fj)
#pragma unroll
      for (int reg = 0; reg < 4; ++reg) {
        float v = comb[fi][fj][reg];
        int row = r0 + fi * 16 + kq * 4 + reg;
        int col = c0 + fj * 16 + rq;
        outAdj[(size_t)row * NT + col] = v;
        part[fj] += v;
      }
#pragma unroll
  for (int fj = 0; fj < 2; ++fj) {
    float p = part[fj];
    p += __shfl_xor(p, 16);
    p += __shfl_xor(p, 32);
    if (kq == 0) csred[w][fj * 16 + rq] = p;
  }

  bool mir = (bi != bj);
  if (mir) {
    // mirror write via per-wave LDS transpose (XOR-swizzled); row sums on the fly
    float* T = ldsT + w * 1024;
#pragma unroll
    for (int fi = 0; fi < 2; ++fi)
#pragma unroll
      for (int fj = 0; fj < 2; ++fj)
#pragma unroll
        for (int reg = 0; reg < 4; ++reg) {
          int r = fi * 16 + kq * 4 + reg;
          int c = fj * 16 + rq;
          T[c * 32 + (r ^ ((c & 15) << 1))] = comb[fi][fj][reg];
        }
    int hl = lane >> 5, l32 = lane & 31;
    float rsum = 0.f;
#pragma unroll
    for (int cc = 0; cc < 16; ++cc) {
      int c = cc * 2 + hl;
      float v = T[c * 32 + (l32 ^ ((c & 15) << 1))];
      rsum += v;
      outAdj[(size_t)(rowB + wc * 32 + c) * NT + r0 + l32] = v;
    }
    rsum += __shfl_xor(rsum, 32);
    if (lane < 32) rsred[w][l32] = rsum;
  }
  __syncthreads();
  if (tid < 128) {
    int c = tid, g = c >> 5, l = c & 31;
    float v = csred[g][l] + csred[4 + g][l] + csred[8 + g][l] + csred[12 + g][l];
    fcsPart[(size_t)bi * NT + bj * 128 + c] = v;
  } else if (tid < 256 && mir) {
    int r = tid - 128, g = r >> 5, l = r & 31;
    float v = rsred[g * 4 + 0][l] + rsred[g * 4 + 1][l] + rsred[g * 4 + 2][l] + rsred[g * 4 + 3][l];
    fcsPart[(size_t)bj * NT + bi * 128 + r] = v;
  }
}

__global__ void k_fcs(const float* __restrict__ fcsPart, float* __restrict__ fcs) {
  int c = blockIdx.x * 256 + threadIdx.x;
  float s = 0.f;
  for (int x = 0; x < 32; ++x) s += fcsPart[(size_t)x * NT + c];
  fcs[c] = s;
}

__global__ void k_scale(float* __restrict__ adj, const float* __restrict__ finalcs) {
  size_t idx = (size_t)blockIdx.x * 256 + threadIdx.x;
  int c = (int)(idx & (NT - 1));
  adj[idx] = adj[idx] / fmaxf(finalcs[c], 1e-12f);
}

// Cpart[kb][M][64] = Arows(bf16 [M][K-chunk]) . Brows(bf16 [64][K-chunk]) (plain store)
__global__ __launch_bounds__(256, 2) void k_gemmT(const bf16_t* __restrict__ A,
                                                  const bf16_t* __restrict__ Bt,
                                                  float* __restrict__ Cpart, int K, int kchunk,
                                                  int m64) {
  int tid = threadIdx.x, lane = tid & 63, w = tid >> 6;
  int rq = lane & 15, kq = lane >> 4;
  int r0 = blockIdx.x * 128 + w * 32;
  int kb = blockIdx.y * kchunk;
  float* Cs = Cpart + (size_t)blockIdx.y * m64;
  f32x4 acc[2][4];
#pragma unroll
  for (int i = 0; i < 2; ++i)
#pragma unroll
    for (int j = 0; j < 4; ++j) acc[i][j] = 0.f;
  const bf16_t* Ap = A + (size_t)(r0 + rq) * K + kb + kq * 8;
  const bf16_t* Bp = Bt + (size_t)rq * K + kb + kq * 8;
#pragma unroll 2
  for (int kc = 0; kc < kchunk; kc += 32) {
    bf16x8 a[2], b[4];
#pragma unroll
    for (int f = 0; f < 2; ++f) a[f] = *(const bf16x8*)(Ap + (size_t)(f * 16) * K + kc);
#pragma unroll
    for (int f = 0; f < 4; ++f) b[f] = *(const bf16x8*)(Bp + (size_t)(f * 16) * K + kc);
#pragma unroll
    for (int fi = 0; fi < 2; ++fi)
#pragma unroll
      for (int fj = 0; fj < 4; ++fj)
        acc[fi][fj] = mfma_bf16(a[fi], b[fj], acc[fi][fj]);
  }
#pragma unroll
  for (int fi = 0; fi < 2; ++fi)
#pragma unroll
    for (int fj = 0; fj < 4; ++fj)
#pragma unroll
      for (int reg = 0; reg < 4; ++reg) {
        int row = r0 + fi * 16 + kq * 4 + reg;
        int col = fj * 16 + rq;
        Cs[(size_t)row * 64 + col] = acc[fi][fj][reg];
      }
}

// out[i] = sum_{s<8} part[s*n + i]
__global__ void k_red8(const float* __restrict__ part, int n, float* __restrict__ out) {
  int i = blockIdx.x * 256 + threadIdx.x;
  if (i >= n) return;
  float s = 0.f;
#pragma unroll
  for (int q = 0; q < 8; ++q) s += part[(size_t)q * n + i];
  out[i] = s;
}

// ---------------- f32 tile GEMMs (precision-sensitive tail) ----------------

__global__ __launch_bounds__(256) void k_gemm_n64(const float* __restrict__ A, int K,
                                                  const float* __restrict__ B,
                                                  float* __restrict__ C,
                                                  const float* __restrict__ bias, int relu) {
  __shared__ float As[64][68], Bs[64][68];
  int r0 = blockIdx.x * 64;
  int tid = threadIdx.x, tx = tid & 15, ty = tid >> 4;
  float acc[4][4] = {};
  for (int kc = 0; kc < K; kc += 64) {
    __syncthreads();
#pragma unroll
    for (int m = 0; m < 16; ++m) {
      int lin = tid + 256 * m;
      int row = lin >> 6, col = lin & 63;
      As[col][row] = A[(size_t)(r0 + row) * K + kc + col];
      Bs[row][col] = B[(size_t)(kc + row) * 64 + col];
    }
    __syncthreads();
#pragma unroll 8
    for (int k = 0; k < 64; ++k) {
      float a[4], b[4];
#pragma unroll
      for (int i = 0; i < 4; ++i) a[i] = As[k][ty * 4 + i];
#pragma unroll
      for (int j = 0; j < 4; ++j) b[j] = Bs[k][tx * 4 + j];
#pragma unroll
      for (int i = 0; i < 4; ++i)
#pragma unroll
        for (int j = 0; j < 4; ++j)
          acc[i][j] = fmaf(a[i], b[j], acc[i][j]);
    }
  }
#pragma unroll
  for (int i = 0; i < 4; ++i)
#pragma unroll
    for (int j = 0; j < 4; ++j) {
      float v = acc[i][j];
      if (bias) v += bias[tx * 4 + j];
      if (relu) v = fmaxf(v, 0.f);
      C[(size_t)(r0 + ty * 4 + i) * 64 + tx * 4 + j] = v;
    }
}

// split-K f32: Cpart[kb][M][64] = A[M][K-chunk] @ B[K][64]  (plain store)
__global__ __launch_bounds__(256) void k_gemm_n64_sk(const float* __restrict__ A, int K,
                                                     int kchunk, const float* __restrict__ B,
                                                     float* __restrict__ Cpart) {
  __shared__ float As[64][68], Bs[64][68];
  int r0 = blockIdx.x * 64;
  int kb = blockIdx.y * kchunk;
  float* Cs = Cpart + (size_t)blockIdx.y * (NT * 64);
  int tid = threadIdx.x, tx = tid & 15, ty = tid >> 4;
  float acc[4][4] = {};
  for (int kc = kb; kc < kb + kchunk; kc += 64) {
    __syncthreads();
#pragma unroll
    for (int m = 0; m < 16; ++m) {
      int lin = tid + 256 * m;
      int row = lin >> 6, col = lin & 63;
      As[col][row] = A[(size_t)(r0 + row) * K + kc + col];
      Bs[row][col] = B[(size_t)(kc + row) * 64 + col];
    }
    __syncthreads();
#pragma unroll 8
    for (int k = 0; k < 64; ++k) {
      float a[4], b[4];
#pragma unroll
      for (int i = 0; i < 4; ++i) a[i] = As[k][ty * 4 + i];
#pragma unroll
      for (int j = 0; j < 4; ++j) b[j] = Bs[k][tx * 4 + j];
#pragma unroll
      for (int i = 0; i < 4; ++i)
#pragma unroll
        for (int j = 0; j < 4; ++j)
          acc[i][j] = fmaf(a[i], b[j], acc[i][j]);
    }
  }
#pragma unroll
  for (int i = 0; i < 4; ++i)
#pragma unroll
    for (int j = 0; j < 4; ++j)
      Cs[(size_t)(r0 + ty * 4 + i) * 64 + tx * 4 + j] = acc[i][j];
}

// X1[i] = relu(sum_{s<8} part[s][i] + b[i&63])
__global__ void k_redbias_relu(const float* __restrict__ part, const float* __restrict__ b,
                               float* __restrict__ X) {
  int i = blockIdx.x * 256 + threadIdx.x;
  float s = 0.f;
#pragma unroll
  for (int q = 0; q < 8; ++q) s += part[(size_t)q * (NT * 64) + i];
  X[i] = fmaxf(s + b[i & 63], 0.f);
}

// P2[r,0:3] = X1[r,:] @ W2
__global__ void k_p2(const float* __restrict__ X1, const float* __restrict__ W2,
                     float* __restrict__ P2) {
  int r = blockIdx.x * 64 + threadIdx.x;
  float a0 = 0.f, a1 = 0.f, a2 = 0.f;
#pragma unroll 8
  for (int k = 0; k < 64; ++k) {
    float x = X1[(size_t)r * 64 + k];
    a0 = fmaf(x, W2[k * 3 + 0], a0);
    a1 = fmaf(x, W2[k * 3 + 1], a1);
    a2 = fmaf(x, W2[k * 3 + 2], a2);
  }
  P2[r * 4 + 0] = a0; P2[r * 4 + 1] = a1; P2[r * 4 + 2] = a2;
}

// logits[r,:] = log_softmax(adj[r,:] @ P2 + b2)
__global__ void k_out(const float* __restrict__ adj, const float* __restrict__ P2,
                      const float* __restrict__ b2, float* __restrict__ logits) {
  int r = blockIdx.x, t = threadIdx.x;  // 64 threads
  const float* arow = adj + (size_t)r * NT;
  float a0 = 0.f, a1 = 0.f, a2 = 0.f;
  for (int c = t; c < NT; c += 64) {
    float a = arow[c];
    a0 = fmaf(a, P2[c * 4 + 0], a0);
    a1 = fmaf(a, P2[c * 4 + 1], a1);
    a2 = fmaf(a, P2[c * 4 + 2], a2);
  }
  for (int off = 32; off; off >>= 1) {
    a0 += __shfl_xor(a0, off);
    a1 += __shfl_xor(a1, off);
    a2 += __shfl_xor(a2, off);
  }
  if (t == 0) {
    a0 += b2[0]; a1 += b2[1]; a2 += b2[2];
    float m = fmaxf(a0, fmaxf(a1, a2));
    float lse = m + logf(expf(a0 - m) + expf(a1 - m) + expf(a2 - m));
    logits[r * 3 + 0] = a0 - lse;
    logits[r * 3 + 1] = a1 - lse;
    logits[r * 3 + 2] = a2 - lse;
  }
}

// ---------------- host ----------------

extern "C" void kernel_launch(void* const* d_in, const int* in_sizes, int n_in,
                              void* d_out, int out_size, void* d_ws, size_t ws_size,
                              hipStream_t stream) {
  (void)in_sizes; (void)n_in; (void)out_size; (void)ws_size;
  const float* features = (const float*)d_in[0];
  const float* adj      = (const float*)d_in[1];
  const float* mp_pap   = (const float*)d_in[2];
  const float* mp_psp   = (const float*)d_in[3];
  const float* fgo_w    = (const float*)d_in[6];
  const float* fpo_w    = (const float*)d_in[7];
  const float* sgg_pap_w = (const float*)d_in[8];
  const float* sgg_psp_w = (const float*)d_in[9];
  const float* sg_agg_w  = (const float*)d_in[10];
  const float* f_agg_f_w = (const float*)d_in[11];
  const float* f_agg_w   = (const float*)d_in[12];
  const float* topo_W_a  = (const float*)d_in[13];
  const float* topo_b_a  = (const float*)d_in[14];
  const float* topo_W_s  = (const float*)d_in[15];
  const float* topo_b_s  = (const float*)d_in[16];
  const float* fgt_w_a   = (const float*)d_in[17];
  const float* fgt_w_s   = (const float*)d_in[18];
  const float* gcn_W1    = (const float*)d_in[19];
  const float* gcn_b1    = (const float*)d_in[20];
  const float* gcn_W2    = (const float*)d_in[21];
  const float* gcn_b2    = (const float*)d_in[22];

  float* logits = (float*)d_out;
  float* adjOut = (float*)d_out + (size_t)NT * 3;      // 4096x4096 f32 output
  bf16_t* simA  = (bf16_t*)adjOut;                     // scratch lifetime before combine

  float* ws = (float*)d_ws;
  size_t o = 0;
  bf16_t* Vg   = (bf16_t*)(ws + o); o += (size_t)NT * 128;   // NT x 256 bf16
  bf16_t* Vfa  = (bf16_t*)(ws + o); o += (size_t)NA * 128;
  bf16_t* Vf0  = (bf16_t*)(ws + o); o += (size_t)NT * 128;
  bf16_t* Vf1  = (bf16_t*)(ws + o); o += (size_t)NT * 128;
  bf16_t* Vpap = (bf16_t*)(ws + o); o += (size_t)NT * 64;    // NT x 128 bf16
  bf16_t* Vpsp = (bf16_t*)(ws + o); o += (size_t)NT * 64;
  bf16_t* Vs0  = (bf16_t*)(ws + o); o += (size_t)NT * 64;
  bf16_t* Vs1  = (bf16_t*)(ws + o); o += (size_t)NT * 64;
  bf16_t* Vfs  = (bf16_t*)(ws + o); o += (size_t)NS * 128;
  bf16_t* simS = (bf16_t*)(ws + o); o += (size_t)NS * NS / 2;
  bf16_t* WaT  = (bf16_t*)(ws + o); o += (size_t)64 * NA / 2;
  bf16_t* WsT  = (bf16_t*)(ws + o); o += (size_t)64 * NS / 2;
  float* fpa  = ws + o; o += (size_t)NT * 128;
  float* fps  = ws + o; o += (size_t)NT * 128;
  float* Sa   = ws + o; o += (size_t)NA * 64;
  float* Ss   = ws + o; o += (size_t)NS * 64;
  float* SaPart = ws + o; o += (size_t)8 * NA * 64;
  float* SsPart = ws + o; o += (size_t)8 * NS * 64;
  float* topoA = ws + o; o += (size_t)NT * 64;
  float* topoS = ws + o; o += (size_t)NT * 64;
  float* H1   = ws + o; o += (size_t)NT * 64;
  float* X1   = ws + o; o += (size_t)NT * 64;
  float* X1Part = ws + o; o += (size_t)8 * NT * 64;
  float* P2   = ws + o; o += (size_t)NT * 4;
  float* csPart = ws + o; o += (size_t)32 * 7 * NT;
  float* fcsPart = ws + o; o += (size_t)32 * NT;
  float* fcs  = ws + o; o += NT;
  float* coef = ws + o; o += (size_t)7 * NT;
  float* w8   = ws + o; o += 8;

  k_weights<<<1, 1, 0, stream>>>(sg_agg_w, f_agg_f_w, f_agg_w, w8);

  // normalized head-weighted feature vectors (bf16)
  k_rownorm<<<NT, 64, 0, stream>>>(features, 128, fgo_w, Vg);
  k_rownorm<<<NT, 64, 0, stream>>>(mp_pap, 64, sgg_pap_w, Vpap);
  k_rownorm<<<NT, 64, 0, stream>>>(mp_psp, 64, sgg_psp_w, Vpsp);
  k_rownorm<<<NA, 64, 0, stream>>>(features + (size_t)NT * 128, 128, fgo_w, Vfa);
  k_rownorm<<<NS, 64, 0, stream>>>(features + (size_t)(NT + NA) * 128, 128, fgo_w, Vfs);

  // feat_prop = ori_g @ fmat_r  (sparse ballot-scan)
  k_spmm128<<<NT, 128, 0, stream>>>(adj, NT, NA, features + (size_t)NT * 128, fpa);
  k_spmm128<<<NT, 128, 0, stream>>>(adj, NT + NA, NS, features + (size_t)(NT + NA) * 128, fps);
  k_rownorm<<<NT, 64, 0, stream>>>(fpa, 128, fpo_w, Vf0);
  k_rownorm<<<NT, 64, 0, stream>>>(fps, 128, fpo_w, Vf1);

  // topo weight transposes (bf16 rows)
  k_transp<<<(NA * 64) / 256, 256, 0, stream>>>(topo_W_a, NA, WaT);
  k_transp<<<(NS * 64) / 256, 256, 0, stream>>>(topo_W_s, NS, WsT);

  // sim_r (thresholded, bf16, LDS-staged) and S_r = sim_r @ topo_W (MFMA split-K)
  k_gram_sim<<<dim3(NA / 128, NA / 128), 1024, 0, stream>>>(Vfa, NA, 256, 0.1f, simA);
  k_gram_sim<<<dim3(NS / 128, NS / 128), 1024, 0, stream>>>(Vfs, NS, 256, 0.1f, simS);
  k_gemmT<<<dim3(NA / 128, 8), 256, 0, stream>>>(simA, WaT, SaPart, NA, NA / 8, NA * 64);
  k_gemmT<<<dim3(NS / 128, 8), 256, 0, stream>>>(simS, WsT, SsPart, NS, NS / 8, NS * 64);
  k_red8<<<(NA * 64) / 256, 256, 0, stream>>>(SaPart, NA * 64, Sa);
  k_red8<<<(NS * 64) / 256, 256, 0, stream>>>(SsPart, NS * 64, Ss);

  // topo_hid = ori_g @ S_r + b
  k_spmm64<<<NT, 128, 0, stream>>>(adj, NT, NA, Sa, topo_b_a, topoA);
  k_spmm64<<<NT, 128, 0, stream>>>(adj, NT + NA, NS, Ss, topo_b_s, topoS);
  k_rownorm<<<NT, 64, 0, stream>>>(topoA, 64, fgt_w_a, Vs0);
  k_rownorm<<<NT, 64, 0, stream>>>(topoS, 64, fgt_w_s, Vs1);

  // pass 1: per-channel column sums (LDS-staged, channel-split, no atomics)
  k_colsum7<<<dim3((NBLK * (NBLK + 1)) / 2, 7), 1024, 0, stream>>>(
      Vg, Vpap, Vpsp, Vf0, Vf1, Vs0, Vs1, csPart);
  k_coef<<<NT / 256, 256, 0, stream>>>(csPart, w8, coef);

  // pass 2: combine + symmetrize (LDS-staged), triangle + transposed mirror
  k_combine<<<(NBLK * (NBLK + 1)) / 2, 1024, 0, stream>>>(Vg, Vpap, Vpsp, Vf0, Vf1, Vs0, Vs1,
                                                          coef, adjOut, fcsPart);
  k_fcs<<<NT / 256, 256, 0, stream>>>(fcsPart, fcs);
  k_scale<<<(NT * NT) / 256, 256, 0, stream>>>(adjOut, fcs);

  // GCN (f32 tail, split-K partials + fused reduce)
  k_gemm_n64<<<NT / 64, 256, 0, stream>>>(features, 128, gcn_W1, H1, nullptr, 0);
  k_gemm_n64_sk<<<dim3(NT / 64, 8), 256, 0, stream>>>(adjOut, NT, NT / 8, H1, X1Part);
  k_redbias_relu<<<(NT * 64) / 256, 256, 0, stream>>>(X1Part, gcn_b1, X1);
  k_p2<<<NT / 64, 64, 0, stream>>>(X1, gcn_W2, P2);
  k_out<<<NT, 64, 0, stream>>>(adjOut, P2, gcn_b2, logits);
}